// Round 1
// 404.583 us; speedup vs baseline: 1.0049x; 1.0049x over previous
//
#include <hip/hip_runtime.h>
#include <math.h>

// ---------------------------------------------------------------------------
// CausalHFPLayer: B=4, N=4096, D=1024, C=64 -> nc=64 chunks/batch, BC=256
// rfft bins M=33, k_low=4, high bins 29. NH=16, NKV=4, HD=64, T=256.
// Round 5: EP_HIGH GEMM rebuilt as 256^2-tile, 8-wave, 4-slot LDS ring with
// counted vmcnt (never drains in main loop) — T3+T4 from the technique
// catalog. Other GEMMs keep the 128^2 m97 structure (too few tiles for 256^2).
// ---------------------------------------------------------------------------

typedef __bf16 bf16_t;
typedef bf16_t bf16x8 __attribute__((ext_vector_type(8)));
typedef float f32x4 __attribute__((ext_vector_type(4)));

#define EP_NONE 0
#define EP_SIGMOID 1
#define EP_FUSELOW 2
#define EP_HIGH 3

// async global->LDS 16B copy. LDS dest is wave-uniform base + lane*16, so the
// lds pointer must be identical across the wave's lanes (m104/m108).
__device__ __forceinline__ void gld_lds16(const bf16_t* g, bf16_t* l) {
  __builtin_amdgcn_global_load_lds(
      (const __attribute__((address_space(1))) unsigned int*)g,
      (__attribute__((address_space(3))) unsigned int*)l, 16, 0, 0);
}

// ============================ DFT (rfft) kernel ============================
// thread = (bc, d). 64 time samples -> 33 complex bins. Xh is bf16:
// Xh[bc][f][d] real rows 0..32, imag rows 33..65. Also emits contiguous bf16
// X_low pack [b*256+t][1024] and bf16 chunk-mean (bin0/64).
__global__ __launch_bounds__(256) void dft_kernel(const float* __restrict__ X,
                                                  bf16_t* __restrict__ Xh,
                                                  bf16_t* __restrict__ XLr,
                                                  bf16_t* __restrict__ XLi,
                                                  bf16_t* __restrict__ gmean) {
  const int d = blockIdx.x * 256 + threadIdx.x;
  const long bc = blockIdx.y;
  const int b = (int)(bc >> 6), ch = (int)(bc & 63);
  const float* xp = X + (bc * 64) * 1024 + d;
  float x[64];
#pragma unroll
  for (int t = 0; t < 64; t++) x[t] = xp[(long)t * 1024];
#pragma unroll
  for (int t = 0; t < 32; t++) {
    float a = x[t], bb = x[t + 32];
    x[t] = a + bb;
    x[t + 32] = a - bb;
  }
  bf16_t* outp = Xh + bc * 66 * 1024 + d;
  const float W = -6.283185307179586f / 64.f;
  for (int f = 0; f <= 32; f += 2) {
    float sd, cd;
    __sincosf(W * f, &sd, &cd);
    float c = 1.f, s = 0.f, ar = 0.f, ai = 0.f;
#pragma unroll
    for (int t = 0; t < 32; t++) {
      ar = fmaf(x[t], c, ar);
      ai = fmaf(x[t], s, ai);
      float cn = c * cd - s * sd;
      s = s * cd + c * sd;
      c = cn;
    }
    outp[(long)f * 1024] = (bf16_t)ar;
    outp[(long)(33 + f) * 1024] = (bf16_t)ai;
    if (f < 4) {
      long xr = ((long)(b * 256 + ch * 4 + f)) * 1024 + d;
      XLr[xr] = (bf16_t)ar;
      XLi[xr] = (bf16_t)ai;
    }
    if (f == 0) gmean[bc * 1024 + d] = (bf16_t)(ar * (1.f / 64.f));
  }
  for (int f = 1; f <= 31; f += 2) {
    float sd, cd;
    __sincosf(W * f, &sd, &cd);
    float c = 1.f, s = 0.f, ar = 0.f, ai = 0.f;
#pragma unroll
    for (int t = 0; t < 32; t++) {
      ar = fmaf(x[32 + t], c, ar);
      ai = fmaf(x[32 + t], s, ai);
      float cn = c * cd - s * sd;
      s = s * cd + c * sd;
      c = cn;
    }
    outp[(long)f * 1024] = (bf16_t)ar;
    outp[(long)(33 + f) * 1024] = (bf16_t)ai;
    if (f < 4) {
      long xr = ((long)(b * 256 + ch * 4 + f)) * 1024 + d;
      XLr[xr] = (bf16_t)ar;
      XLi[xr] = (bf16_t)ai;
    }
  }
}

// ==================== weight concat / convert to bf16 ======================
__global__ __launch_bounds__(256) void concat_w(const float* __restrict__ qw,
                                                const float* __restrict__ kw,
                                                const float* __restrict__ vw,
                                                bf16_t* __restrict__ W) {
  int i = blockIdx.x * 256 + threadIdx.x;  // float4 index, total 393216
  float4 v;
  if (i < 262144) v = ((const float4*)qw)[i];
  else if (i < 327680) v = ((const float4*)kw)[i - 262144];
  else v = ((const float4*)vw)[i - 327680];
  bf16_t* o = W + (long)i * 4;
  o[0] = (bf16_t)v.x; o[1] = (bf16_t)v.y; o[2] = (bf16_t)v.z; o[3] = (bf16_t)v.w;
}

// one kernel converts 4 weight matrices (z selects), 262144 float4 each
__global__ __launch_bounds__(256) void cvt4_bf16(const float* __restrict__ s0,
                                                 const float* __restrict__ s1,
                                                 const float* __restrict__ s2,
                                                 const float* __restrict__ s3,
                                                 bf16_t* __restrict__ d0,
                                                 bf16_t* __restrict__ d1,
                                                 bf16_t* __restrict__ d2,
                                                 bf16_t* __restrict__ d3) {
  int i = blockIdx.x * 256 + threadIdx.x;
  const float* s = blockIdx.y == 0 ? s0 : blockIdx.y == 1 ? s1 : blockIdx.y == 2 ? s2 : s3;
  bf16_t* dst = blockIdx.y == 0 ? d0 : blockIdx.y == 1 ? d1 : blockIdx.y == 2 ? d2 : d3;
  float4 v = ((const float4*)s)[i];
  bf16_t* o = dst + (long)i * 4;
  o[0] = (bf16_t)v.x; o[1] = (bf16_t)v.y; o[2] = (bf16_t)v.z; o[3] = (bf16_t)v.w;
}

// ============================ bf16 MFMA GEMM ===============================
// C[M,N] = A[M,K] @ B[N,K]^T. 128x128 tile, BK=32, 2x2 waves x 4x4 mfma,
// global_load_lds(16B) staging into unpadded [row][k] LDS (m97 structure).
// Used for the small-M GEMMs (QKV / gate / O-proj) where a 256^2 tile would
// leave most CUs idle.
template <int EMODE>
__global__ __launch_bounds__(256) void mmbf_kernel(
    const bf16_t* __restrict__ A0, const bf16_t* __restrict__ A1,
    const bf16_t* __restrict__ B0, const bf16_t* __restrict__ B1,
    int N, int K,
    void* __restrict__ C0v, void* __restrict__ C1v,
    const bf16_t* __restrict__ E0, const bf16_t* __restrict__ E1,
    bf16_t* __restrict__ XhMut,
    const float* __restrict__ gate, const float* __restrict__ alpha_ptr) {
  constexpr int BM = 128, BN = 128, BK = 32;  // no pad: lane-order layout
  __shared__ bf16_t As[BM * BK];
  __shared__ bf16_t Bs[BN * BK];
  const int z = blockIdx.z;
  const bf16_t* A = z ? A1 : A0;
  const bf16_t* B = z ? B1 : B0;
  void* Cv = z ? C1v : C0v;
  const bf16_t* E = z ? E1 : E0;
  const int imoff = z ? 33 * 1024 : 0;
  const int tid = threadIdx.x;
  const int lane = tid & 63;
  const int wave = tid >> 6;
  const int wm = (wave & 1) * 64, wn = (wave >> 1) * 64;
  const int m0 = blockIdx.x * BM, n0 = blockIdx.y * BN;
  const int q = lane >> 4, mr = lane & 15;
  // staging: lane -> (row within 16-row wave group, 8-elem k group)
  const int lrow = lane >> 2, lk8 = (lane & 3) * 8;

  f32x4 acc[4][4];
#pragma unroll
  for (int i = 0; i < 4; i++)
#pragma unroll
    for (int j = 0; j < 4; j++) acc[i][j] = (f32x4){0.f, 0.f, 0.f, 0.f};

  const long arow0 = (long)(m0 + wave * 16 + lrow) * K + lk8;
  const long brow0 = (long)(n0 + wave * 16 + lrow) * K + lk8;

  for (int kb = 0; kb < K; kb += BK) {
#pragma unroll
    for (int it = 0; it < 2; it++) {
      // wave w stages rows [w*16 + it*64, +16); LDS base wave-uniform
      gld_lds16(A + arow0 + (long)it * 64 * K + kb, As + (wave * 16 + it * 64) * BK);
      gld_lds16(B + brow0 + (long)it * 64 * K + kb, Bs + (wave * 16 + it * 64) * BK);
    }
    __syncthreads();  // drains vmcnt(0) -> LDS tiles complete
    bf16x8 af[4], bfr[4];
#pragma unroll
    for (int mi = 0; mi < 4; mi++)
      af[mi] = *(const bf16x8*)&As[(wm + mi * 16 + mr) * BK + q * 8];
#pragma unroll
    for (int ni = 0; ni < 4; ni++)
      bfr[ni] = *(const bf16x8*)&Bs[(wn + ni * 16 + mr) * BK + q * 8];
#pragma unroll
    for (int mi = 0; mi < 4; mi++)
#pragma unroll
      for (int ni = 0; ni < 4; ni++)
        acc[mi][ni] = __builtin_amdgcn_mfma_f32_16x16x32_bf16(
            af[mi], bfr[ni], acc[mi][ni], 0, 0, 0);
    __syncthreads();  // LDS reads done before next stage overwrites
  }

  float alpha = 0.f;
  if constexpr (EMODE == EP_FUSELOW) alpha = 1.f / (1.f + __expf(-alpha_ptr[0]));
#pragma unroll
  for (int mi = 0; mi < 4; mi++) {
#pragma unroll
    for (int ni = 0; ni < 4; ni++) {
      int col = n0 + wn + ni * 16 + mr;
      int rbase = m0 + wm + mi * 16 + q * 4;
#pragma unroll
      for (int r = 0; r < 4; r++) {
        int row = rbase + r;
        float val = acc[mi][ni][r];
        if constexpr (EMODE == EP_NONE) {
          ((bf16_t*)Cv)[(long)row * N + col] = (bf16_t)val;
        } else if constexpr (EMODE == EP_SIGMOID) {
          ((float*)Cv)[(long)row * N + col] = 1.f / (1.f + __expf(-val));
        } else if constexpr (EMODE == EP_FUSELOW) {
          // E = contiguous bf16 X_low pack, same row/col indexing as C
          float xl = (float)E[(long)row * 1024 + col];
          ((float*)Cv)[(long)row * 1024 + col] = alpha * val + (1.f - alpha) * xl;
        } else {  // EP_HIGH: in-place A_high = val*g + X_high (Xh bf16)
          int bc = row / 29, l = row - bc * 29;
          long x = ((long)bc * 66 + 4 + l) * 1024 + imoff + col;
          XhMut[x] = (bf16_t)fmaf(val, gate[(long)bc * 1024 + col], (float)XhMut[x]);
        }
      }
    }
  }
}

// ================= 256^2-tile pipelined GEMM for EP_HIGH ===================
// C[7424,1024] = A[7424,1024] @ B[1024,1024]^T, epilogue: Xh high rows
// += C*gate (in place). 512 threads = 8 waves (2M x 4N), per-wave 128x64 out.
// BK=32, LDS ring of 4 slots (4 x 32 KiB = 128 KiB), depth-3 prefetch with
// counted s_waitcnt vmcnt(8) — staging loads stay in flight across barriers
// (T3+T4). Raw s_barrier (NOT __syncthreads: that would drain vmcnt to 0).
// Race-freedom: slot (t+3)&3 == (t-1)&3 whose reads all completed before this
// iteration's barrier (per-wave lgkmcnt before t-1's MFMAs, then barrier).
__global__ __launch_bounds__(512, 2) void gemm256_high(
    const bf16_t* __restrict__ A0, const bf16_t* __restrict__ A1,
    const bf16_t* __restrict__ B0, const bf16_t* __restrict__ B1,
    bf16_t* __restrict__ XhMut, const float* __restrict__ gate) {
  constexpr int K = 1024;
  constexpr int NT = K / 32;  // 32 K-tiles
  __shared__ bf16_t lds[4][2][256 * 32];  // [ring][A|B][row*32+k] = 128 KiB

  // block-id swizzle: XCD = id%8 gets ~4 consecutive m-panels with all their
  // (n,z) tiles -> A panels (512 KB each) stay L2-resident per XCD.
  const int id = blockIdx.x;                 // 232 blocks
  const int kk = (id & 7) * 29 + (id >> 3);  // bijection [0,232)
  const int mt = kk >> 3, rem = kk & 7;
  const int nt = rem & 3, z = rem >> 2;
  const bf16_t* A = z ? A1 : A0;
  const bf16_t* B = z ? B1 : B0;
  const int imoff = z ? 33 * 1024 : 0;
  const int m0 = mt * 256, n0 = nt * 256;

  const int tid = threadIdx.x;
  const int lane = tid & 63, wave = tid >> 6;
  const int wm = (wave & 1) * 128, wn = (wave >> 1) * 64;
  const int q = lane >> 4, mr = lane & 15;
  // staging: chunk c = rd*512 + tid covers row c>>2, k-bytes (c&3)*16
  const int srow = tid >> 2, sk8 = (tid & 3) * 8;

  f32x4 acc[8][4];
#pragma unroll
  for (int i = 0; i < 8; i++)
#pragma unroll
    for (int j = 0; j < 4; j++) acc[i][j] = (f32x4){0.f, 0.f, 0.f, 0.f};

  // stage K-tile t into ring slot t&3: 4 x gld_lds16 per thread (2 A + 2 B)
  auto stage = [&](int t) {
    const int bi = t & 3;
    const int kb = t * 32;
#pragma unroll
    for (int rd = 0; rd < 2; rd++) {
      gld_lds16(A + (long)(m0 + rd * 128 + srow) * K + kb + sk8,
                &lds[bi][0][(rd * 512 + wave * 64) * 8]);
      gld_lds16(B + (long)(n0 + rd * 128 + srow) * K + kb + sk8,
                &lds[bi][1][(rd * 512 + wave * 64) * 8]);
    }
  };

  stage(0);
  stage(1);
  stage(2);

  for (int t = 0; t < NT; t++) {
    // tile t landed; tiles t+1,t+2 (8 loads/thread) remain in flight.
    if (t < NT - 2)
      asm volatile("s_waitcnt vmcnt(8)" ::: "memory");
    else if (t == NT - 2)
      asm volatile("s_waitcnt vmcnt(4)" ::: "memory");
    else
      asm volatile("s_waitcnt vmcnt(0)" ::: "memory");
    __builtin_amdgcn_s_barrier();  // all waves' tile-t LDS writes now visible
    if (t + 3 < NT) stage(t + 3);  // slot freed before this barrier

    const bf16_t* As_ = &lds[t & 3][0][0];
    const bf16_t* Bs_ = &lds[t & 3][1][0];
    bf16x8 af[8], bfr[4];
#pragma unroll
    for (int mi = 0; mi < 8; mi++)
      af[mi] = *(const bf16x8*)&As_[(wm + mi * 16 + mr) * 32 + q * 8];
#pragma unroll
    for (int ni = 0; ni < 4; ni++)
      bfr[ni] = *(const bf16x8*)&Bs_[(wn + ni * 16 + mr) * 32 + q * 8];
    __builtin_amdgcn_s_setprio(1);
#pragma unroll
    for (int mi = 0; mi < 8; mi++)
#pragma unroll
      for (int ni = 0; ni < 4; ni++)
        acc[mi][ni] = __builtin_amdgcn_mfma_f32_16x16x32_bf16(
            af[mi], bfr[ni], acc[mi][ni], 0, 0, 0);
    __builtin_amdgcn_s_setprio(0);
  }

  // epilogue: Xh[bc][4+l][:] += C * gate[bc][:]  (rows: row = bc*29 + l)
#pragma unroll
  for (int mi = 0; mi < 8; mi++) {
#pragma unroll
    for (int r = 0; r < 4; r++) {
      int row = m0 + wm + mi * 16 + q * 4 + r;
      int bc = row / 29, l = row - bc * 29;
      long xbase = ((long)bc * 66 + 4 + l) * 1024 + imoff;
      const float* gp = gate + (long)bc * 1024;
#pragma unroll
      for (int ni = 0; ni < 4; ni++) {
        int col = n0 + wn + ni * 16 + mr;
        long x = xbase + col;
        XhMut[x] = (bf16_t)fmaf(acc[mi][ni][r], gp[col], (float)XhMut[x]);
      }
    }
  }
}

// ====================== MFMA flash attention ===============================
// grid (NH=16, B*4 qtiles=16, 2). block 256 = 4 waves; wave w owns q rows
// [qt*64 + w*16, +16). Block-causal (chunk=4): kt<qt visible, kt==qt masked.
__global__ __launch_bounds__(256) void attn_mfma(const bf16_t* __restrict__ QKVr,
                                                 const bf16_t* __restrict__ QKVi,
                                                 bf16_t* __restrict__ Or_,
                                                 bf16_t* __restrict__ Oi_) {
  const int h = blockIdx.x;
  const int b = blockIdx.y >> 2, qt = blockIdx.y & 3;
  const bf16_t* QKV = blockIdx.z ? QKVi : QKVr;
  bf16_t* O = blockIdx.z ? Oi_ : Or_;
  const int kvh = h >> 2;
  const int tid = threadIdx.x;
  const int lane = tid & 63, wave = tid >> 6;
  const int mr = lane & 15, q4 = lane >> 4;

  __shared__ bf16_t Ks[64 * 72];
  __shared__ bf16_t Vt[64 * 72];
  __shared__ bf16_t Ps[4][16 * 72];

  bf16x8 af[2];
  {
    const bf16_t* qp =
        QKV + (long)(b * 256 + qt * 64 + wave * 16 + mr) * 1536 + h * 64;
    af[0] = *(const bf16x8*)(qp + q4 * 8);
    af[1] = *(const bf16x8*)(qp + 32 + q4 * 8);
  }
  f32x4 Oacc[4];
#pragma unroll
  for (int ni = 0; ni < 4; ni++) Oacc[ni] = (f32x4){0.f, 0.f, 0.f, 0.f};
  float mrow[4], lrow[4];
#pragma unroll
  for (int r = 0; r < 4; r++) { mrow[r] = -1e30f; lrow[r] = 0.f; }

  for (int kt = 0; kt <= qt; kt++) {
#pragma unroll
    for (int it = 0; it < 2; it++) {
      int idx = tid + it * 256;
      int key = idx >> 3, dg = idx & 7;
      const bf16_t* kp = QKV + (long)(b * 256 + kt * 64 + key) * 1536 + 1024 +
                         kvh * 64 + dg * 8;
      *(bf16x8*)&Ks[key * 72 + dg * 8] = *(const bf16x8*)kp;
      bf16x8 vv = *(const bf16x8*)(kp + 256);
#pragma unroll
      for (int j = 0; j < 8; j++) Vt[(dg * 8 + j) * 72 + key] = vv[j];
    }
    __syncthreads();

    f32x4 S[4];
#pragma unroll
    for (int ni = 0; ni < 4; ni++) {
      S[ni] = (f32x4){0.f, 0.f, 0.f, 0.f};
#pragma unroll
      for (int s = 0; s < 2; s++) {
        bf16x8 kb = *(const bf16x8*)&Ks[(ni * 16 + mr) * 72 + s * 32 + q4 * 8];
        S[ni] = __builtin_amdgcn_mfma_f32_16x16x32_bf16(af[s], kb, S[ni], 0, 0, 0);
      }
    }
#pragma unroll
    for (int ni = 0; ni < 4; ni++) {
#pragma unroll
      for (int r = 0; r < 4; r++) {
        float v = S[ni][r] * 0.125f;
        if (kt == qt) {
          int qrow = wave * 16 + q4 * 4 + r;
          int kcol = ni * 16 + mr;
          if ((qrow >> 2) < (kcol >> 2)) v = -1e30f;
        }
        S[ni][r] = v;
      }
    }
#pragma unroll
    for (int r = 0; r < 4; r++) {
      float mx = fmaxf(fmaxf(S[0][r], S[1][r]), fmaxf(S[2][r], S[3][r]));
#pragma unroll
      for (int off = 1; off < 16; off <<= 1) mx = fmaxf(mx, __shfl_xor(mx, off));
      float mn = fmaxf(mrow[r], mx);
      float sc = __expf(mrow[r] - mn);
      mrow[r] = mn;
      float rs = 0.f;
#pragma unroll
      for (int ni = 0; ni < 4; ni++) {
        float p = __expf(S[ni][r] - mn);
        rs += p;
        Ps[wave][(q4 * 4 + r) * 72 + ni * 16 + mr] = (bf16_t)p;
      }
#pragma unroll
      for (int off = 1; off < 16; off <<= 1) rs += __shfl_xor(rs, off);
      lrow[r] = lrow[r] * sc + rs;
#pragma unroll
      for (int ni = 0; ni < 4; ni++) Oacc[ni][r] *= sc;
    }
    bf16x8 pa[2];
    pa[0] = *(const bf16x8*)&Ps[wave][mr * 72 + q4 * 8];
    pa[1] = *(const bf16x8*)&Ps[wave][mr * 72 + 32 + q4 * 8];
#pragma unroll
    for (int ni = 0; ni < 4; ni++) {
#pragma unroll
      for (int s = 0; s < 2; s++) {
        bf16x8 vb = *(const bf16x8*)&Vt[(ni * 16 + mr) * 72 + s * 32 + q4 * 8];
        Oacc[ni] = __builtin_amdgcn_mfma_f32_16x16x32_bf16(pa[s], vb, Oacc[ni], 0, 0, 0);
      }
    }
    __syncthreads();
  }

#pragma unroll
  for (int r = 0; r < 4; r++) {
    float inv = 1.f / lrow[r];
    long row = b * 256 + qt * 64 + wave * 16 + q4 * 4 + r;
#pragma unroll
    for (int ni = 0; ni < 4; ni++)
      O[row * 1024 + h * 64 + ni * 16 + mr] = (bf16_t)(Oacc[ni][r] * inv);
  }
}

// ===================== depthwise causal conv + GELU ========================
__global__ __launch_bounds__(256) void dwconv_kernel(const bf16_t* __restrict__ Xh,
                                                     const float* __restrict__ dwr,
                                                     const float* __restrict__ dwi,
                                                     bf16_t* __restrict__ Gr,
                                                     bf16_t* __restrict__ Gi) {
  const int d = blockIdx.x * 256 + threadIdx.x;
  const int bc = blockIdx.y;
  const float* dw = blockIdx.z ? dwi : dwr;
  bf16_t* G = blockIdx.z ? Gi : Gr;
  const int imoff = blockIdx.z ? 33 * 1024 : 0;
  float w[7];
#pragma unroll
  for (int j = 0; j < 7; j++) w[j] = dw[d * 7 + j];
  float x[29];
#pragma unroll
  for (int l = 0; l < 29; l++)
    x[l] = (float)Xh[((long)bc * 66 + 4 + l) * 1024 + imoff + d];
#pragma unroll
  for (int l = 0; l < 29; l++) {
    float y = 0.f;
#pragma unroll
    for (int j = 0; j < 7; j++) {
      int src = l - 6 + j;
      if (src >= 0) y = fmaf(w[j], x[src], y);
    }
    float ge = 0.5f * y * (1.f + erff(y * 0.7071067811865475f));
    G[((long)bc * 29 + l) * 1024 + d] = (bf16_t)ge;
  }
}

// ============================ irfft + output ===============================
// Bins 0..3 from Af fp32 (alpha-fused low), 4..32 from bf16 Xh (= A_high
// in-place). Imag of bins 0/32 ignored (pocketfft c2r).
__global__ __launch_bounds__(256) void irfft_kernel(const bf16_t* __restrict__ Xh,
                                                    const float* __restrict__ Afr,
                                                    const float* __restrict__ Afi,
                                                    float* __restrict__ out) {
  const int d = blockIdx.x * 256 + threadIdx.x;
  const int bc = blockIdx.y;
  const int b = bc >> 6, t0 = (bc & 63) << 2;
  const long afbase = ((long)(b * 256 + t0)) * 1024 + d;
  const long xbase = (long)bc * 66 * 1024 + d;
  const float W = 6.283185307179586f / 64.f;
  float E[32], Od[32];
#pragma unroll
  for (int t = 0; t < 32; t++) { E[t] = 0.f; Od[t] = 0.f; }
  const float R0 = Afr[afbase];
  const float R32 = (float)Xh[xbase + 32 * 1024];
  for (int f = 2; f <= 30; f += 2) {
    float Rf = (f < 4) ? Afr[afbase + (long)f * 1024] : (float)Xh[xbase + (long)f * 1024];
    float If = (f < 4) ? Afi[afbase + (long)f * 1024]
                       : (float)Xh[xbase + (long)(33 + f) * 1024];
    float a = 2.f * Rf, bb = -2.f * If;
    float sd, cd;
    __sincosf(W * f, &sd, &cd);
    float c = 1.f, s = 0.f;
#pragma unroll
    for (int t = 0; t < 32; t++) {
      E[t] = fmaf(a, c, fmaf(bb, s, E[t]));
      float cn = c * cd - s * sd;
      s = s * cd + c * sd;
      c = cn;
    }
  }
  for (int f = 1; f <= 31; f += 2) {
    float Rf = (f < 4) ? Afr[afbase + (long)f * 1024] : (float)Xh[xbase + (long)f * 1024];
    float If = (f < 4) ? Afi[afbase + (long)f * 1024]
                       : (float)Xh[xbase + (long)(33 + f) * 1024];
    float a = 2.f * Rf, bb = -2.f * If;
    float sd, cd;
    __sincosf(W * f, &sd, &cd);
    float c = 1.f, s = 0.f;
#pragma unroll
    for (int t = 0; t < 32; t++) {
      Od[t] = fmaf(a, c, fmaf(bb, s, Od[t]));
      float cn = c * cd - s * sd;
      s = s * cd + c * sd;
      c = cn;
    }
  }
#pragma unroll
  for (int t = 0; t < 32; t++) {
    float base = R0 + ((t & 1) ? -R32 : R32);
    out[((long)(bc * 64 + t)) * 1024 + d] = (base + E[t] + Od[t]) * (1.f / 64.f);
    out[((long)(bc * 64 + t + 32)) * 1024 + d] = (base + E[t] - Od[t]) * (1.f / 64.f);
  }
}

// ============================ launcher =====================================
extern "C" void kernel_launch(void* const* d_in, const int* in_sizes, int n_in,
                              void* d_out, int out_size, void* d_ws, size_t ws_size,
                              hipStream_t stream) {
  const float* hidden = (const float*)d_in[0];
  const float* q_w = (const float*)d_in[1];
  const float* k_w = (const float*)d_in[2];
  const float* v_w = (const float*)d_in[3];
  const float* o_w = (const float*)d_in[4];
  const float* dw_r = (const float*)d_in[5];
  const float* pw_r = (const float*)d_in[6];
  const float* dw_i = (const float*)d_in[7];
  const float* pw_i = (const float*)d_in[8];
  const float* gate_w = (const float*)d_in[9];
  const float* alpha_raw = (const float*)d_in[10];
  float* out = (float*)d_out;

  float* ws = (float*)d_ws;
  // fp32 region
  float* Afr = ws;                       // 1024*1024
  float* Afi = Afr + 1048576;
  float* gg = Afi + 1048576;             // 256*1024
  // bf16 region
  bf16_t* bws = (bf16_t*)(gg + 262144);
  bf16_t* Xh = bws;                      // 256*66*1024 = 17,301,504 bf16
  bf16_t* Wqkv_b = Xh + 17301504;        // 1536*1024
  bf16_t* ow_b = Wqkv_b + 1572864;       // 1024*1024
  bf16_t* gw_b = ow_b + 1048576;
  bf16_t* pwr_b = gw_b + 1048576;
  bf16_t* pwi_b = pwr_b + 1048576;
  bf16_t* XLr = pwi_b + 1048576;         // 1024*1024
  bf16_t* XLi = XLr + 1048576;
  bf16_t* gmean = XLi + 1048576;         // 256*1024
  bf16_t* QKVbr = gmean + 262144;        // 1024*1536
  bf16_t* QKVbi = QKVbr + 1572864;
  bf16_t* Obr = QKVbi + 1572864;         // 1024*1024
  bf16_t* Obi = Obr + 1048576;
  bf16_t* Gr = Obi + 1048576;            // 7424*1024
  bf16_t* Gi = Gr + 7602176;             // total ~103 MB

  // 1) rfft -> bf16 Xh + bf16 X_low pack + bf16 chunk-mean
  dft_kernel<<<dim3(4, 256), 256, 0, stream>>>(hidden, Xh, XLr, XLi, gmean);
  // 2) weights -> bf16
  concat_w<<<1536, 256, 0, stream>>>(q_w, k_w, v_w, Wqkv_b);
  cvt4_bf16<<<dim3(1024, 4), 256, 0, stream>>>(o_w, gate_w, pw_r, pw_i,
                                               ow_b, gw_b, pwr_b, pwi_b);
  // 3) QKV projections (real & imag via z), bf16 out
  mmbf_kernel<EP_NONE><<<dim3(8, 12, 2), 256, 0, stream>>>(
      XLr, XLi, Wqkv_b, Wqkv_b, 1536, 1024, QKVbr, QKVbi, nullptr, nullptr,
      nullptr, nullptr, nullptr);
  // 4) gate = sigmoid(mean @ gate_w^T)  (gmean already /64)
  mmbf_kernel<EP_SIGMOID><<<dim3(2, 8, 1), 256, 0, stream>>>(
      gmean, gmean, gw_b, gw_b, 1024, 1024, gg, gg, nullptr, nullptr,
      nullptr, nullptr, nullptr);
  // 5) MFMA flash attention (real & imag), bf16 O out
  attn_mfma<<<dim3(16, 16, 2), 256, 0, stream>>>(QKVbr, QKVbi, Obr, Obi);
  // 6) O projection + alpha*A_low + (1-alpha)*X_low -> fp32 Af
  mmbf_kernel<EP_FUSELOW><<<dim3(8, 8, 2), 256, 0, stream>>>(
      Obr, Obi, ow_b, ow_b, 1024, 1024, Afr, Afi, XLr, XLi,
      nullptr, nullptr, alpha_raw);
  // 7) depthwise causal conv + exact GELU on high bins, bf16 out
  dwconv_kernel<<<dim3(4, 256, 2), 256, 0, stream>>>(Xh, dw_r, dw_i, Gr, Gi);
  // 8) pointwise conv + gate + residual, in-place into bf16 Xh high rows:
  //    256^2-tile pipelined GEMM, counted-vmcnt ring (T3+T4)
  gemm256_high<<<dim3(232), 512, 0, stream>>>(Gr, Gi, pwr_b, pwi_b, Xh, gg);
  // 9) irfft -> output
  irfft_kernel<<<dim3(4, 256), 256, 0, stream>>>(Xh, Afr, Afi, out);
}

// Round 2
// 347.931 us; speedup vs baseline: 1.1685x; 1.1628x over previous
//
#include <hip/hip_runtime.h>
#include <math.h>

// ---------------------------------------------------------------------------
// CausalHFPLayer: B=4, N=4096, D=1024, C=64 -> nc=64 chunks/batch, BC=256
// rfft bins M=33, k_low=4, high bins 29. NH=16, NKV=4, HD=64, T=256.
// Round 6: irfft rewritten as MFMA GEMM (basis bf16 hi+res, fp32 low-bin
// epilogue). gemm256_high gets T2 read-swizzle (pre-swizzled global source,
// rule #21) + sched_barrier(0) after manual waitcnts.
// ---------------------------------------------------------------------------

typedef __bf16 bf16_t;
typedef bf16_t bf16x8 __attribute__((ext_vector_type(8)));
typedef float f32x4 __attribute__((ext_vector_type(4)));

#define EP_NONE 0
#define EP_SIGMOID 1
#define EP_FUSELOW 2
#define EP_HIGH 3

// async global->LDS 16B copy. LDS dest is wave-uniform base + lane*16, so the
// lds pointer must be identical across the wave's lanes (m104/m108).
__device__ __forceinline__ void gld_lds16(const bf16_t* g, bf16_t* l) {
  __builtin_amdgcn_global_load_lds(
      (const __attribute__((address_space(1))) unsigned int*)g,
      (__attribute__((address_space(3))) unsigned int*)l, 16, 0, 0);
}

// ============================ DFT (rfft) kernel ============================
// thread = (bc, d). 64 time samples -> 33 complex bins. Xh is bf16:
// Xh[bc][f][d] real rows 0..32, imag rows 33..65. Also emits contiguous bf16
// X_low pack [b*256+t][1024] and bf16 chunk-mean (bin0/64).
__global__ __launch_bounds__(256) void dft_kernel(const float* __restrict__ X,
                                                  bf16_t* __restrict__ Xh,
                                                  bf16_t* __restrict__ XLr,
                                                  bf16_t* __restrict__ XLi,
                                                  bf16_t* __restrict__ gmean) {
  const int d = blockIdx.x * 256 + threadIdx.x;
  const long bc = blockIdx.y;
  const int b = (int)(bc >> 6), ch = (int)(bc & 63);
  const float* xp = X + (bc * 64) * 1024 + d;
  float x[64];
#pragma unroll
  for (int t = 0; t < 64; t++) x[t] = xp[(long)t * 1024];
#pragma unroll
  for (int t = 0; t < 32; t++) {
    float a = x[t], bb = x[t + 32];
    x[t] = a + bb;
    x[t + 32] = a - bb;
  }
  bf16_t* outp = Xh + bc * 66 * 1024 + d;
  const float W = -6.283185307179586f / 64.f;
  for (int f = 0; f <= 32; f += 2) {
    float sd, cd;
    __sincosf(W * f, &sd, &cd);
    float c = 1.f, s = 0.f, ar = 0.f, ai = 0.f;
#pragma unroll
    for (int t = 0; t < 32; t++) {
      ar = fmaf(x[t], c, ar);
      ai = fmaf(x[t], s, ai);
      float cn = c * cd - s * sd;
      s = s * cd + c * sd;
      c = cn;
    }
    outp[(long)f * 1024] = (bf16_t)ar;
    outp[(long)(33 + f) * 1024] = (bf16_t)ai;
    if (f < 4) {
      long xr = ((long)(b * 256 + ch * 4 + f)) * 1024 + d;
      XLr[xr] = (bf16_t)ar;
      XLi[xr] = (bf16_t)ai;
    }
    if (f == 0) gmean[bc * 1024 + d] = (bf16_t)(ar * (1.f / 64.f));
  }
  for (int f = 1; f <= 31; f += 2) {
    float sd, cd;
    __sincosf(W * f, &sd, &cd);
    float c = 1.f, s = 0.f, ar = 0.f, ai = 0.f;
#pragma unroll
    for (int t = 0; t < 32; t++) {
      ar = fmaf(x[32 + t], c, ar);
      ai = fmaf(x[32 + t], s, ai);
      float cn = c * cd - s * sd;
      s = s * cd + c * sd;
      c = cn;
    }
    outp[(long)f * 1024] = (bf16_t)ar;
    outp[(long)(33 + f) * 1024] = (bf16_t)ai;
    if (f < 4) {
      long xr = ((long)(b * 256 + ch * 4 + f)) * 1024 + d;
      XLr[xr] = (bf16_t)ar;
      XLi[xr] = (bf16_t)ai;
    }
  }
}

// ==================== weight concat / convert to bf16 ======================
__global__ __launch_bounds__(256) void concat_w(const float* __restrict__ qw,
                                                const float* __restrict__ kw,
                                                const float* __restrict__ vw,
                                                bf16_t* __restrict__ W) {
  int i = blockIdx.x * 256 + threadIdx.x;  // float4 index, total 393216
  float4 v;
  if (i < 262144) v = ((const float4*)qw)[i];
  else if (i < 327680) v = ((const float4*)kw)[i - 262144];
  else v = ((const float4*)vw)[i - 327680];
  bf16_t* o = W + (long)i * 4;
  o[0] = (bf16_t)v.x; o[1] = (bf16_t)v.y; o[2] = (bf16_t)v.z; o[3] = (bf16_t)v.w;
}

// one kernel converts 4 weight matrices (z selects), 262144 float4 each
__global__ __launch_bounds__(256) void cvt4_bf16(const float* __restrict__ s0,
                                                 const float* __restrict__ s1,
                                                 const float* __restrict__ s2,
                                                 const float* __restrict__ s3,
                                                 bf16_t* __restrict__ d0,
                                                 bf16_t* __restrict__ d1,
                                                 bf16_t* __restrict__ d2,
                                                 bf16_t* __restrict__ d3) {
  int i = blockIdx.x * 256 + threadIdx.x;
  const float* s = blockIdx.y == 0 ? s0 : blockIdx.y == 1 ? s1 : blockIdx.y == 2 ? s2 : s3;
  bf16_t* dst = blockIdx.y == 0 ? d0 : blockIdx.y == 1 ? d1 : blockIdx.y == 2 ? d2 : d3;
  float4 v = ((const float4*)s)[i];
  bf16_t* o = dst + (long)i * 4;
  o[0] = (bf16_t)v.x; o[1] = (bf16_t)v.y; o[2] = (bf16_t)v.z; o[3] = (bf16_t)v.w;
}

// ====================== irfft basis tables (constant) ======================
// High-bin basis T[64 t][64 k] (k: 0..28 -> Rf f=4..32; 29..56 -> If f=4..31;
// 57..63 zero pad), stored PRE-SWIZZLED for the irfft LDS read pattern:
// element (t,k) lives at t*64 + ((k>>3)^(t&7))*8 + (k&7). Split bf16 hi +
// bf16 residual so the effective basis precision is ~fp32.
// Tlow[64 t][8]: fp32 {1/64, 2c1/64, -2s1/64, 2c2/64, -2s2/64, 2c3/64,
// -2s3/64, 0} for the fp32 low-bin epilogue.
__global__ __launch_bounds__(256) void mk_basis(bf16_t* __restrict__ bhi,
                                                bf16_t* __restrict__ bres,
                                                float* __restrict__ tlow) {
  int idx = blockIdx.x * 256 + threadIdx.x;
  const float TW = 6.283185307179586f / 64.f;
  if (idx < 4096) {
    int t = idx >> 6, k = idx & 63;
    float v = 0.f;
    if (k < 28) {
      int ft = ((4 + k) * t) & 63;
      v = 2.f * cosf(TW * (float)ft) * (1.f / 64.f);
    } else if (k == 28) {  // f=32 Nyquist: (-1)^t / 64 (single-counted)
      int ft = (32 * t) & 63;
      v = cosf(TW * (float)ft) * (1.f / 64.f);
    } else if (k < 57) {
      int ft = ((k - 25) * t) & 63;
      v = -2.f * sinf(TW * (float)ft) * (1.f / 64.f);
    }
    bf16_t h = (bf16_t)v;
    float res = v - (float)h;
    int addr = t * 64 + (((k >> 3) ^ (t & 7)) << 3) + (k & 7);
    bhi[addr] = h;
    bres[addr] = (bf16_t)res;
  } else if (idx < 4608) {
    int i = idx - 4096;
    int t = i >> 3, j = i & 7;
    float v = 0.f;
    if (j == 0) v = 1.f / 64.f;
    else if (j < 7) {
      int f = (j + 1) >> 1;  // 1,1,2,2,3,3
      int ft = (f * t) & 63;
      float th = TW * (float)ft;
      v = (j & 1) ? 2.f * cosf(th) * (1.f / 64.f)
                  : -2.f * sinf(th) * (1.f / 64.f);
    }
    tlow[i] = v;
  }
}

// ============================ bf16 MFMA GEMM ===============================
// C[M,N] = A[M,K] @ B[N,K]^T. 128x128 tile, BK=32, 2x2 waves x 4x4 mfma,
// global_load_lds(16B) staging into unpadded [row][k] LDS (m97 structure).
// Used for the small-M GEMMs (QKV / gate / O-proj).
template <int EMODE>
__global__ __launch_bounds__(256) void mmbf_kernel(
    const bf16_t* __restrict__ A0, const bf16_t* __restrict__ A1,
    const bf16_t* __restrict__ B0, const bf16_t* __restrict__ B1,
    int N, int K,
    void* __restrict__ C0v, void* __restrict__ C1v,
    const bf16_t* __restrict__ E0, const bf16_t* __restrict__ E1,
    bf16_t* __restrict__ XhMut,
    const float* __restrict__ gate, const float* __restrict__ alpha_ptr) {
  constexpr int BM = 128, BN = 128, BK = 32;  // no pad: lane-order layout
  __shared__ bf16_t As[BM * BK];
  __shared__ bf16_t Bs[BN * BK];
  const int z = blockIdx.z;
  const bf16_t* A = z ? A1 : A0;
  const bf16_t* B = z ? B1 : B0;
  void* Cv = z ? C1v : C0v;
  const bf16_t* E = z ? E1 : E0;
  const int imoff = z ? 33 * 1024 : 0;
  const int tid = threadIdx.x;
  const int lane = tid & 63;
  const int wave = tid >> 6;
  const int wm = (wave & 1) * 64, wn = (wave >> 1) * 64;
  const int m0 = blockIdx.x * BM, n0 = blockIdx.y * BN;
  const int q = lane >> 4, mr = lane & 15;
  // staging: lane -> (row within 16-row wave group, 8-elem k group)
  const int lrow = lane >> 2, lk8 = (lane & 3) * 8;

  f32x4 acc[4][4];
#pragma unroll
  for (int i = 0; i < 4; i++)
#pragma unroll
    for (int j = 0; j < 4; j++) acc[i][j] = (f32x4){0.f, 0.f, 0.f, 0.f};

  const long arow0 = (long)(m0 + wave * 16 + lrow) * K + lk8;
  const long brow0 = (long)(n0 + wave * 16 + lrow) * K + lk8;

  for (int kb = 0; kb < K; kb += BK) {
#pragma unroll
    for (int it = 0; it < 2; it++) {
      // wave w stages rows [w*16 + it*64, +16); LDS base wave-uniform
      gld_lds16(A + arow0 + (long)it * 64 * K + kb, As + (wave * 16 + it * 64) * BK);
      gld_lds16(B + brow0 + (long)it * 64 * K + kb, Bs + (wave * 16 + it * 64) * BK);
    }
    __syncthreads();  // drains vmcnt(0) -> LDS tiles complete
    bf16x8 af[4], bfr[4];
#pragma unroll
    for (int mi = 0; mi < 4; mi++)
      af[mi] = *(const bf16x8*)&As[(wm + mi * 16 + mr) * BK + q * 8];
#pragma unroll
    for (int ni = 0; ni < 4; ni++)
      bfr[ni] = *(const bf16x8*)&Bs[(wn + ni * 16 + mr) * BK + q * 8];
#pragma unroll
    for (int mi = 0; mi < 4; mi++)
#pragma unroll
      for (int ni = 0; ni < 4; ni++)
        acc[mi][ni] = __builtin_amdgcn_mfma_f32_16x16x32_bf16(
            af[mi], bfr[ni], acc[mi][ni], 0, 0, 0);
    __syncthreads();  // LDS reads done before next stage overwrites
  }

  float alpha = 0.f;
  if constexpr (EMODE == EP_FUSELOW) alpha = 1.f / (1.f + __expf(-alpha_ptr[0]));
#pragma unroll
  for (int mi = 0; mi < 4; mi++) {
#pragma unroll
    for (int ni = 0; ni < 4; ni++) {
      int col = n0 + wn + ni * 16 + mr;
      int rbase = m0 + wm + mi * 16 + q * 4;
#pragma unroll
      for (int r = 0; r < 4; r++) {
        int row = rbase + r;
        float val = acc[mi][ni][r];
        if constexpr (EMODE == EP_NONE) {
          ((bf16_t*)Cv)[(long)row * N + col] = (bf16_t)val;
        } else if constexpr (EMODE == EP_SIGMOID) {
          ((float*)Cv)[(long)row * N + col] = 1.f / (1.f + __expf(-val));
        } else if constexpr (EMODE == EP_FUSELOW) {
          // E = contiguous bf16 X_low pack, same row/col indexing as C
          float xl = (float)E[(long)row * 1024 + col];
          ((float*)Cv)[(long)row * 1024 + col] = alpha * val + (1.f - alpha) * xl;
        } else {  // EP_HIGH: in-place A_high = val*g + X_high (Xh bf16)
          int bc = row / 29, l = row - bc * 29;
          long x = ((long)bc * 66 + 4 + l) * 1024 + imoff + col;
          XhMut[x] = (bf16_t)fmaf(val, gate[(long)bc * 1024 + col], (float)XhMut[x]);
        }
      }
    }
  }
}

// ================= 256^2-tile pipelined GEMM for EP_HIGH ===================
// C[7424,1024] = A[7424,1024] @ B[1024,1024]^T, epilogue: Xh high rows
// += C*gate (in place). 512 threads = 8 waves (2M x 4N), per-wave 128x64 out.
// BK=32, LDS ring of 4 slots, depth-3 prefetch with counted vmcnt.
// Round 6: T2 read-swizzle (slot = q ^ (row&3)) via pre-swizzled GLOBAL
// source (linear LDS dest, rule #21) -> fragment ds_read 8-way -> 4-way
// conflict; sched_barrier(0) after each hand waitcnt (rule #18).
__global__ __launch_bounds__(512, 2) void gemm256_high(
    const bf16_t* __restrict__ A0, const bf16_t* __restrict__ A1,
    const bf16_t* __restrict__ B0, const bf16_t* __restrict__ B1,
    bf16_t* __restrict__ XhMut, const float* __restrict__ gate) {
  constexpr int K = 1024;
  constexpr int NT = K / 32;  // 32 K-tiles
  __shared__ bf16_t lds[4][2][256 * 32];  // [ring][A|B][row*32+k] = 128 KiB

  // block-id swizzle: XCD = id%8 gets ~4 consecutive m-panels with all their
  // (n,z) tiles -> A panels stay L2-resident per XCD.
  const int id = blockIdx.x;                 // 232 blocks
  const int kk = (id & 7) * 29 + (id >> 3);  // bijection [0,232)
  const int mt = kk >> 3, rem = kk & 7;
  const int nt = rem & 3, z = rem >> 2;
  const bf16_t* A = z ? A1 : A0;
  const bf16_t* B = z ? B1 : B0;
  const int imoff = z ? 33 * 1024 : 0;
  const int m0 = mt * 256, n0 = nt * 256;

  const int tid = threadIdx.x;
  const int lane = tid & 63, wave = tid >> 6;
  const int wm = (wave & 1) * 128, wn = (wave >> 1) * 64;
  const int q = lane >> 4, mr = lane & 15;
  // staging: chunk c = rd*512 + tid covers row c>>2; the 16B k-slot fetched
  // from global is (c&3)^(row&3) so that LDS[row][slot] = G[row][slot^(row&3)]
  const int srow = tid >> 2;
  const int gk8 = (((tid & 3) ^ ((tid >> 2) & 3)) << 3);

  f32x4 acc[8][4];
#pragma unroll
  for (int i = 0; i < 8; i++)
#pragma unroll
    for (int j = 0; j < 4; j++) acc[i][j] = (f32x4){0.f, 0.f, 0.f, 0.f};

  // stage K-tile t into ring slot t&3: 4 x gld_lds16 per thread (2 A + 2 B)
  auto stage = [&](int t) {
    const int bi = t & 3;
    const int kb = t * 32;
#pragma unroll
    for (int rd = 0; rd < 2; rd++) {
      gld_lds16(A + (long)(m0 + rd * 128 + srow) * K + kb + gk8,
                &lds[bi][0][(rd * 512 + wave * 64) * 8]);
      gld_lds16(B + (long)(n0 + rd * 128 + srow) * K + kb + gk8,
                &lds[bi][1][(rd * 512 + wave * 64) * 8]);
    }
  };

  stage(0);
  stage(1);
  stage(2);

  const int asl = (q ^ (mr & 3)) * 8;  // swizzled 8-elem k-slot for frags

  for (int t = 0; t < NT; t++) {
    // tile t landed; tiles t+1,t+2 (8 loads/thread) remain in flight.
    if (t < NT - 2)
      asm volatile("s_waitcnt vmcnt(8)" ::: "memory");
    else if (t == NT - 2)
      asm volatile("s_waitcnt vmcnt(4)" ::: "memory");
    else
      asm volatile("s_waitcnt vmcnt(0)" ::: "memory");
    __builtin_amdgcn_sched_barrier(0);
    __builtin_amdgcn_s_barrier();  // all waves' tile-t LDS writes now visible
    if (t + 3 < NT) stage(t + 3);  // slot freed before this barrier

    const bf16_t* As_ = &lds[t & 3][0][0];
    const bf16_t* Bs_ = &lds[t & 3][1][0];
    bf16x8 bfr[4];
#pragma unroll
    for (int ni = 0; ni < 4; ni++)
      bfr[ni] = *(const bf16x8*)&Bs_[(wn + ni * 16 + mr) * 32 + asl];
    __builtin_amdgcn_s_setprio(1);
#pragma unroll
    for (int mi = 0; mi < 8; mi++) {
      bf16x8 af = *(const bf16x8*)&As_[(wm + mi * 16 + mr) * 32 + asl];
#pragma unroll
      for (int ni = 0; ni < 4; ni++)
        acc[mi][ni] = __builtin_amdgcn_mfma_f32_16x16x32_bf16(
            af, bfr[ni], acc[mi][ni], 0, 0, 0);
    }
    __builtin_amdgcn_s_setprio(0);
  }

  // epilogue: Xh[bc][4+l][:] += C * gate[bc][:]  (rows: row = bc*29 + l)
#pragma unroll
  for (int mi = 0; mi < 8; mi++) {
#pragma unroll
    for (int r = 0; r < 4; r++) {
      int row = m0 + wm + mi * 16 + q * 4 + r;
      int bc = row / 29, l = row - bc * 29;
      long xbase = ((long)bc * 66 + 4 + l) * 1024 + imoff;
      const float* gp = gate + (long)bc * 1024;
#pragma unroll
      for (int ni = 0; ni < 4; ni++) {
        int col = n0 + wn + ni * 16 + mr;
        long x = xbase + col;
        XhMut[x] = (bf16_t)fmaf(acc[mi][ni][r], gp[col], (float)XhMut[x]);
      }
    }
  }
}

// ====================== MFMA flash attention ===============================
// grid (NH=16, B*4 qtiles=16, 2). block 256 = 4 waves; wave w owns q rows
// [qt*64 + w*16, +16). Block-causal (chunk=4): kt<qt visible, kt==qt masked.
__global__ __launch_bounds__(256) void attn_mfma(const bf16_t* __restrict__ QKVr,
                                                 const bf16_t* __restrict__ QKVi,
                                                 bf16_t* __restrict__ Or_,
                                                 bf16_t* __restrict__ Oi_) {
  const int h = blockIdx.x;
  const int b = blockIdx.y >> 2, qt = blockIdx.y & 3;
  const bf16_t* QKV = blockIdx.z ? QKVi : QKVr;
  bf16_t* O = blockIdx.z ? Oi_ : Or_;
  const int kvh = h >> 2;
  const int tid = threadIdx.x;
  const int lane = tid & 63, wave = tid >> 6;
  const int mr = lane & 15, q4 = lane >> 4;

  __shared__ bf16_t Ks[64 * 72];
  __shared__ bf16_t Vt[64 * 72];
  __shared__ bf16_t Ps[4][16 * 72];

  bf16x8 af[2];
  {
    const bf16_t* qp =
        QKV + (long)(b * 256 + qt * 64 + wave * 16 + mr) * 1536 + h * 64;
    af[0] = *(const bf16x8*)(qp + q4 * 8);
    af[1] = *(const bf16x8*)(qp + 32 + q4 * 8);
  }
  f32x4 Oacc[4];
#pragma unroll
  for (int ni = 0; ni < 4; ni++) Oacc[ni] = (f32x4){0.f, 0.f, 0.f, 0.f};
  float mrow[4], lrow[4];
#pragma unroll
  for (int r = 0; r < 4; r++) { mrow[r] = -1e30f; lrow[r] = 0.f; }

  for (int kt = 0; kt <= qt; kt++) {
#pragma unroll
    for (int it = 0; it < 2; it++) {
      int idx = tid + it * 256;
      int key = idx >> 3, dg = idx & 7;
      const bf16_t* kp = QKV + (long)(b * 256 + kt * 64 + key) * 1536 + 1024 +
                         kvh * 64 + dg * 8;
      *(bf16x8*)&Ks[key * 72 + dg * 8] = *(const bf16x8*)kp;
      bf16x8 vv = *(const bf16x8*)(kp + 256);
#pragma unroll
      for (int j = 0; j < 8; j++) Vt[(dg * 8 + j) * 72 + key] = vv[j];
    }
    __syncthreads();

    f32x4 S[4];
#pragma unroll
    for (int ni = 0; ni < 4; ni++) {
      S[ni] = (f32x4){0.f, 0.f, 0.f, 0.f};
#pragma unroll
      for (int s = 0; s < 2; s++) {
        bf16x8 kb = *(const bf16x8*)&Ks[(ni * 16 + mr) * 72 + s * 32 + q4 * 8];
        S[ni] = __builtin_amdgcn_mfma_f32_16x16x32_bf16(af[s], kb, S[ni], 0, 0, 0);
      }
    }
#pragma unroll
    for (int ni = 0; ni < 4; ni++) {
#pragma unroll
      for (int r = 0; r < 4; r++) {
        float v = S[ni][r] * 0.125f;
        if (kt == qt) {
          int qrow = wave * 16 + q4 * 4 + r;
          int kcol = ni * 16 + mr;
          if ((qrow >> 2) < (kcol >> 2)) v = -1e30f;
        }
        S[ni][r] = v;
      }
    }
#pragma unroll
    for (int r = 0; r < 4; r++) {
      float mx = fmaxf(fmaxf(S[0][r], S[1][r]), fmaxf(S[2][r], S[3][r]));
#pragma unroll
      for (int off = 1; off < 16; off <<= 1) mx = fmaxf(mx, __shfl_xor(mx, off));
      float mn = fmaxf(mrow[r], mx);
      float sc = __expf(mrow[r] - mn);
      mrow[r] = mn;
      float rs = 0.f;
#pragma unroll
      for (int ni = 0; ni < 4; ni++) {
        float p = __expf(S[ni][r] - mn);
        rs += p;
        Ps[wave][(q4 * 4 + r) * 72 + ni * 16 + mr] = (bf16_t)p;
      }
#pragma unroll
      for (int off = 1; off < 16; off <<= 1) rs += __shfl_xor(rs, off);
      lrow[r] = lrow[r] * sc + rs;
#pragma unroll
      for (int ni = 0; ni < 4; ni++) Oacc[ni][r] *= sc;
    }
    bf16x8 pa[2];
    pa[0] = *(const bf16x8*)&Ps[wave][mr * 72 + q4 * 8];
    pa[1] = *(const bf16x8*)&Ps[wave][mr * 72 + 32 + q4 * 8];
#pragma unroll
    for (int ni = 0; ni < 4; ni++) {
#pragma unroll
      for (int s = 0; s < 2; s++) {
        bf16x8 vb = *(const bf16x8*)&Vt[(ni * 16 + mr) * 72 + s * 32 + q4 * 8];
        Oacc[ni] = __builtin_amdgcn_mfma_f32_16x16x32_bf16(pa[s], vb, Oacc[ni], 0, 0, 0);
      }
    }
    __syncthreads();
  }

#pragma unroll
  for (int r = 0; r < 4; r++) {
    float inv = 1.f / lrow[r];
    long row = b * 256 + qt * 64 + wave * 16 + q4 * 4 + r;
#pragma unroll
    for (int ni = 0; ni < 4; ni++)
      O[row * 1024 + h * 64 + ni * 16 + mr] = (bf16_t)(Oacc[ni][r] * inv);
  }
}

// ===================== depthwise causal conv + GELU ========================
__global__ __launch_bounds__(256) void dwconv_kernel(const bf16_t* __restrict__ Xh,
                                                     const float* __restrict__ dwr,
                                                     const float* __restrict__ dwi,
                                                     bf16_t* __restrict__ Gr,
                                                     bf16_t* __restrict__ Gi) {
  const int d = blockIdx.x * 256 + threadIdx.x;
  const int bc = blockIdx.y;
  const float* dw = blockIdx.z ? dwi : dwr;
  bf16_t* G = blockIdx.z ? Gi : Gr;
  const int imoff = blockIdx.z ? 33 * 1024 : 0;
  float w[7];
#pragma unroll
  for (int j = 0; j < 7; j++) w[j] = dw[d * 7 + j];
  float x[29];
#pragma unroll
  for (int l = 0; l < 29; l++)
    x[l] = (float)Xh[((long)bc * 66 + 4 + l) * 1024 + imoff + d];
#pragma unroll
  for (int l = 0; l < 29; l++) {
    float y = 0.f;
#pragma unroll
    for (int j = 0; j < 7; j++) {
      int src = l - 6 + j;
      if (src >= 0) y = fmaf(w[j], x[src], y);
    }
    float ge = 0.5f * y * (1.f + erff(y * 0.7071067811865475f));
    G[((long)bc * 29 + l) * 1024 + d] = (bf16_t)ge;
  }
}

// ======================= irfft via MFMA + fp32 low =========================
// out[bc*64+t][d] = sum_k T[t][k]*XhHigh[bc][k][d]  (MFMA, basis hi+res bf16)
//                 + fp32 low-bin part from Af (f=0..3) via Tlow.
// Block: one bc x 256 d-cols, 4 waves (each 64 t x 64 d), M=64 K=64.
// B staged transposed into LDS: thread = one d column, 57 coalesced scalar
// loads -> 8 x ds_write_b128, XOR slot swizzle (g^(d&7)) => ~2-way reads.
__global__ __launch_bounds__(256) void irfft_mfma(
    const bf16_t* __restrict__ Xh, const float* __restrict__ Afr,
    const float* __restrict__ Afi, const bf16_t* __restrict__ bhi,
    const bf16_t* __restrict__ bres, const float* __restrict__ tlow,
    float* __restrict__ out) {
  const int bc = blockIdx.y;        // 0..255
  const int d0 = blockIdx.x * 256;  // 4 d-tiles
  const int tid = threadIdx.x;
  const int lane = tid & 63, wave = tid >> 6;
  const int mr = lane & 15, q = lane >> 4;
  const int wn = wave * 64;

  __shared__ bf16_t Ahi[64 * 64];
  __shared__ bf16_t Ares[64 * 64];
  __shared__ bf16_t Bs[256 * 64];
  __shared__ float Tl[64 * 8];

  // basis tables: linear gld_lds (already pre-swizzled in global)
  gld_lds16(bhi + (wave * 64 + lane) * 8, Ahi + wave * 64 * 8);
  gld_lds16(bhi + (256 + wave * 64 + lane) * 8, Ahi + (256 + wave * 64) * 8);
  gld_lds16(bres + (wave * 64 + lane) * 8, Ares + wave * 64 * 8);
  gld_lds16(bres + (256 + wave * 64 + lane) * 8, Ares + (256 + wave * 64) * 8);
  if (tid < 128) ((float4*)Tl)[tid] = ((const float4*)tlow)[tid];

  // B transpose-stage: thread owns d-column (d0+tid); rows k=0..56 map to
  // Xh rows 4..32 (real f=4..32) and 37..64 (imag f=4..31); 57..63 zero.
  {
    const bf16_t* xc = Xh + (long)bc * 66 * 1024 + d0 + tid;
    const int sw = tid & 7;
#pragma unroll
    for (int g = 0; g < 8; g++) {
      bf16x8 v;
#pragma unroll
      for (int i = 0; i < 8; i++) {
        int j = g * 8 + i;
        int row = (j < 29) ? (4 + j) : (8 + j);
        v[i] = (j < 57) ? xc[(long)row * 1024] : (bf16_t)0.f;
      }
      *(bf16x8*)&Bs[tid * 64 + ((g ^ sw) << 3)] = v;
    }
  }
  __syncthreads();  // drains vmcnt -> basis complete; ds_writes complete

  f32x4 acc[4][4];
#pragma unroll
  for (int i = 0; i < 4; i++)
#pragma unroll
    for (int j = 0; j < 4; j++) acc[i][j] = (f32x4){0.f, 0.f, 0.f, 0.f};

#pragma unroll
  for (int s = 0; s < 2; s++) {
    bf16x8 bfv[4];
#pragma unroll
    for (int ni = 0; ni < 4; ni++) {
      int dcol = wn + ni * 16 + mr;
      bfv[ni] = *(const bf16x8*)&Bs[dcol * 64 + (((s * 4 + q) ^ (dcol & 7)) << 3)];
    }
#pragma unroll
    for (int mi = 0; mi < 4; mi++) {
      int trow = mi * 16 + mr;
      int so = (((s * 4 + q) ^ (trow & 7)) << 3);
      bf16x8 ah = *(const bf16x8*)&Ahi[trow * 64 + so];
      bf16x8 ar = *(const bf16x8*)&Ares[trow * 64 + so];
#pragma unroll
      for (int ni = 0; ni < 4; ni++) {
        acc[mi][ni] = __builtin_amdgcn_mfma_f32_16x16x32_bf16(
            ah, bfv[ni], acc[mi][ni], 0, 0, 0);
        acc[mi][ni] = __builtin_amdgcn_mfma_f32_16x16x32_bf16(
            ar, bfv[ni], acc[mi][ni], 0, 0, 0);
      }
    }
  }

  // fp32 low-bin epilogue: rows f=0..3 of Af (alpha-fused), Tlow basis
  const int arow = (bc >> 6) * 256 + (bc & 63) * 4;
  float R[4][7];
#pragma unroll
  for (int ni = 0; ni < 4; ni++) {
    long ab = (long)arow * 1024 + d0 + wn + ni * 16 + mr;
    R[ni][0] = Afr[ab];
    R[ni][1] = Afr[ab + 1024];
    R[ni][2] = Afi[ab + 1024];
    R[ni][3] = Afr[ab + 2048];
    R[ni][4] = Afi[ab + 2048];
    R[ni][5] = Afr[ab + 3072];
    R[ni][6] = Afi[ab + 3072];
  }
  const long obase = ((long)bc * 64) * 1024 + d0;
#pragma unroll
  for (int mi = 0; mi < 4; mi++) {
#pragma unroll
    for (int r = 0; r < 4; r++) {
      int t = mi * 16 + q * 4 + r;
      const float* tl = &Tl[t * 8];
#pragma unroll
      for (int ni = 0; ni < 4; ni++) {
        float low = tl[0] * R[ni][0];
        low = fmaf(tl[1], R[ni][1], low);
        low = fmaf(tl[2], R[ni][2], low);
        low = fmaf(tl[3], R[ni][3], low);
        low = fmaf(tl[4], R[ni][4], low);
        low = fmaf(tl[5], R[ni][5], low);
        low = fmaf(tl[6], R[ni][6], low);
        out[obase + (long)t * 1024 + wn + ni * 16 + mr] = acc[mi][ni][r] + low;
      }
    }
  }
}

// ============================ launcher =====================================
extern "C" void kernel_launch(void* const* d_in, const int* in_sizes, int n_in,
                              void* d_out, int out_size, void* d_ws, size_t ws_size,
                              hipStream_t stream) {
  const float* hidden = (const float*)d_in[0];
  const float* q_w = (const float*)d_in[1];
  const float* k_w = (const float*)d_in[2];
  const float* v_w = (const float*)d_in[3];
  const float* o_w = (const float*)d_in[4];
  const float* dw_r = (const float*)d_in[5];
  const float* pw_r = (const float*)d_in[6];
  const float* dw_i = (const float*)d_in[7];
  const float* pw_i = (const float*)d_in[8];
  const float* gate_w = (const float*)d_in[9];
  const float* alpha_raw = (const float*)d_in[10];
  float* out = (float*)d_out;

  float* ws = (float*)d_ws;
  // fp32 region
  float* Afr = ws;                       // 1024*1024
  float* Afi = Afr + 1048576;
  float* gg = Afi + 1048576;             // 256*1024
  // bf16 region
  bf16_t* bws = (bf16_t*)(gg + 262144);
  bf16_t* Xh = bws;                      // 256*66*1024 = 17,301,504 bf16
  bf16_t* Wqkv_b = Xh + 17301504;        // 1536*1024
  bf16_t* ow_b = Wqkv_b + 1572864;       // 1024*1024
  bf16_t* gw_b = ow_b + 1048576;
  bf16_t* pwr_b = gw_b + 1048576;
  bf16_t* pwi_b = pwr_b + 1048576;
  bf16_t* XLr = pwi_b + 1048576;         // 1024*1024
  bf16_t* XLi = XLr + 1048576;
  bf16_t* gmean = XLi + 1048576;         // 256*1024
  bf16_t* QKVbr = gmean + 262144;        // 1024*1536
  bf16_t* QKVbi = QKVbr + 1572864;
  bf16_t* Obr = QKVbi + 1572864;         // 1024*1024
  bf16_t* Obi = Obr + 1048576;
  bf16_t* Gr = Obi + 1048576;            // 7424*1024
  bf16_t* Gi = Gr + 7602176;
  bf16_t* bhi = Gi + 7602176;            // 64*64 basis hi
  bf16_t* bres = bhi + 4096;             // 64*64 basis residual
  float* tlowp = (float*)(bres + 4096);  // 64*8 fp32

  // 0) irfft basis tables (pre-swizzled)
  mk_basis<<<18, 256, 0, stream>>>(bhi, bres, tlowp);
  // 1) rfft -> bf16 Xh + bf16 X_low pack + bf16 chunk-mean
  dft_kernel<<<dim3(4, 256), 256, 0, stream>>>(hidden, Xh, XLr, XLi, gmean);
  // 2) weights -> bf16
  concat_w<<<1536, 256, 0, stream>>>(q_w, k_w, v_w, Wqkv_b);
  cvt4_bf16<<<dim3(1024, 4), 256, 0, stream>>>(o_w, gate_w, pw_r, pw_i,
                                               ow_b, gw_b, pwr_b, pwi_b);
  // 3) QKV projections (real & imag via z), bf16 out
  mmbf_kernel<EP_NONE><<<dim3(8, 12, 2), 256, 0, stream>>>(
      XLr, XLi, Wqkv_b, Wqkv_b, 1536, 1024, QKVbr, QKVbi, nullptr, nullptr,
      nullptr, nullptr, nullptr);
  // 4) gate = sigmoid(mean @ gate_w^T)  (gmean already /64)
  mmbf_kernel<EP_SIGMOID><<<dim3(2, 8, 1), 256, 0, stream>>>(
      gmean, gmean, gw_b, gw_b, 1024, 1024, gg, gg, nullptr, nullptr,
      nullptr, nullptr, nullptr);
  // 5) MFMA flash attention (real & imag), bf16 O out
  attn_mfma<<<dim3(16, 16, 2), 256, 0, stream>>>(QKVbr, QKVbi, Obr, Obi);
  // 6) O projection + alpha*A_low + (1-alpha)*X_low -> fp32 Af
  mmbf_kernel<EP_FUSELOW><<<dim3(8, 8, 2), 256, 0, stream>>>(
      Obr, Obi, ow_b, ow_b, 1024, 1024, Afr, Afi, XLr, XLi,
      nullptr, nullptr, alpha_raw);
  // 7) depthwise causal conv + exact GELU on high bins, bf16 out
  dwconv_kernel<<<dim3(4, 256, 2), 256, 0, stream>>>(Xh, dw_r, dw_i, Gr, Gi);
  // 8) pointwise conv + gate + residual, in-place into bf16 Xh high rows
  gemm256_high<<<dim3(232), 512, 0, stream>>>(Gr, Gi, pwr_b, pwi_b, Xh, gg);
  // 9) irfft via MFMA + fp32 low-bin epilogue
  irfft_mfma<<<dim3(4, 256), 256, 0, stream>>>(Xh, Afr, Afi, bhi, bres,
                                               tlowp, out);
}

// Round 3
// 343.613 us; speedup vs baseline: 1.1832x; 1.0126x over previous
//
#include <hip/hip_runtime.h>
#include <math.h>

// ---------------------------------------------------------------------------
// CausalHFPLayer: B=4, N=4096, D=1024, C=64 -> nc=64 chunks/batch, BC=256
// rfft bins M=33, k_low=4, high bins 29. NH=16, NKV=4, HD=64, T=256.
// Round 7: dft rewritten as MFMA GEMM (basis hi+res bf16, DATA hi+res bf16,
// 3-MFMA product => ~fp32 accuracy). gemm256_high swizzle upgraded to
// sigma(r) = ((r&3)+((r>>2)&3))&3 (kills the residual exact 4-way where rows
// mr,mr+4,mr+8,mr+12 shared slot AND bank window).
// ---------------------------------------------------------------------------

typedef __bf16 bf16_t;
typedef bf16_t bf16x8 __attribute__((ext_vector_type(8)));
typedef float f32x4 __attribute__((ext_vector_type(4)));

#define EP_NONE 0
#define EP_SIGMOID 1
#define EP_FUSELOW 2
#define EP_HIGH 3

// async global->LDS 16B copy. LDS dest is wave-uniform base + lane*16, so the
// lds pointer must be identical across the wave's lanes (m104/m108).
__device__ __forceinline__ void gld_lds16(const bf16_t* g, bf16_t* l) {
  __builtin_amdgcn_global_load_lds(
      (const __attribute__((address_space(1))) unsigned int*)g,
      (__attribute__((address_space(3))) unsigned int*)l, 16, 0, 0);
}

// ==================== weight concat / convert to bf16 ======================
__global__ __launch_bounds__(256) void concat_w(const float* __restrict__ qw,
                                                const float* __restrict__ kw,
                                                const float* __restrict__ vw,
                                                bf16_t* __restrict__ W) {
  int i = blockIdx.x * 256 + threadIdx.x;  // float4 index, total 393216
  float4 v;
  if (i < 262144) v = ((const float4*)qw)[i];
  else if (i < 327680) v = ((const float4*)kw)[i - 262144];
  else v = ((const float4*)vw)[i - 327680];
  bf16_t* o = W + (long)i * 4;
  o[0] = (bf16_t)v.x; o[1] = (bf16_t)v.y; o[2] = (bf16_t)v.z; o[3] = (bf16_t)v.w;
}

// one kernel converts 4 weight matrices (z selects), 262144 float4 each
__global__ __launch_bounds__(256) void cvt4_bf16(const float* __restrict__ s0,
                                                 const float* __restrict__ s1,
                                                 const float* __restrict__ s2,
                                                 const float* __restrict__ s3,
                                                 bf16_t* __restrict__ d0,
                                                 bf16_t* __restrict__ d1,
                                                 bf16_t* __restrict__ d2,
                                                 bf16_t* __restrict__ d3) {
  int i = blockIdx.x * 256 + threadIdx.x;
  const float* s = blockIdx.y == 0 ? s0 : blockIdx.y == 1 ? s1 : blockIdx.y == 2 ? s2 : s3;
  bf16_t* dst = blockIdx.y == 0 ? d0 : blockIdx.y == 1 ? d1 : blockIdx.y == 2 ? d2 : d3;
  float4 v = ((const float4*)s)[i];
  bf16_t* o = dst + (long)i * 4;
  o[0] = (bf16_t)v.x; o[1] = (bf16_t)v.y; o[2] = (bf16_t)v.z; o[3] = (bf16_t)v.w;
}

// ====================== fft basis tables (constant) ========================
// dft basis D[80 t-rows][64 k]: row r<33: cos(2*pi*r*k/64); rows 33..65:
// -sin(2*pi*(r-33)*k/64); rows 66..79 zero. Pre-swizzled: element (r,k) at
// r*64 + ((k>>3)^(r&7))*8 + (k&7). Split bf16 hi + residual.
// irfft basis T[64 t][64 k] (k: 0..28 -> Rf f=4..32; 29..56 -> If f=4..31;
// 57..63 zero), same swizzle, same split. Tlow[64 t][8]: fp32 low-bin basis.
__global__ __launch_bounds__(256) void mk_basis(bf16_t* __restrict__ dhi,
                                                bf16_t* __restrict__ dres,
                                                bf16_t* __restrict__ bhi,
                                                bf16_t* __restrict__ bres,
                                                float* __restrict__ tlow) {
  int idx = blockIdx.x * 256 + threadIdx.x;
  const float TW = 6.283185307179586f / 64.f;
  if (idx < 5120) {  // dft basis
    int r = idx >> 6, k = idx & 63;
    float v = 0.f;
    if (r < 33) {
      v = cosf(TW * (float)((r * k) & 63));
    } else if (r < 66) {
      v = -sinf(TW * (float)(((r - 33) * k) & 63));
    }
    bf16_t h = (bf16_t)v;
    float res = v - (float)h;
    int addr = r * 64 + (((k >> 3) ^ (r & 7)) << 3) + (k & 7);
    dhi[addr] = h;
    dres[addr] = (bf16_t)res;
  } else if (idx < 9216) {  // irfft basis
    int i = idx - 5120;
    int t = i >> 6, k = i & 63;
    float v = 0.f;
    if (k < 28) {
      int ft = ((4 + k) * t) & 63;
      v = 2.f * cosf(TW * (float)ft) * (1.f / 64.f);
    } else if (k == 28) {  // f=32 Nyquist: single-counted
      int ft = (32 * t) & 63;
      v = cosf(TW * (float)ft) * (1.f / 64.f);
    } else if (k < 57) {
      int ft = ((k - 25) * t) & 63;
      v = -2.f * sinf(TW * (float)ft) * (1.f / 64.f);
    }
    bf16_t h = (bf16_t)v;
    float res = v - (float)h;
    int addr = t * 64 + (((k >> 3) ^ (t & 7)) << 3) + (k & 7);
    bhi[addr] = h;
    bres[addr] = (bf16_t)res;
  } else if (idx < 9728) {  // tlow
    int i = idx - 9216;
    int t = i >> 3, j = i & 7;
    float v = 0.f;
    if (j == 0) v = 1.f / 64.f;
    else if (j < 7) {
      int f = (j + 1) >> 1;  // 1,1,2,2,3,3
      int ft = (f * t) & 63;
      float th = TW * (float)ft;
      v = (j & 1) ? 2.f * cosf(th) * (1.f / 64.f)
                  : -2.f * sinf(th) * (1.f / 64.f);
    }
    tlow[i] = v;
  }
}

// ========================= DFT (rfft) via MFMA =============================
// Xh[bc][r][d] (r<33 real, 33..65 imag) = sum_t D[r][t] * x[bc][t][d].
// Block: one bc x 256 d-cols, 4 waves. A = basis hi+res (LDS), B = x^T
// hi+res (LDS, XOR slot swizzle). 3 MFMAs per tile: Ah*Bh + Ah*Br + Ar*Bh
// => ~fp32 product accuracy (dropped Ar*Br ~ 2^-18). Also emits the bf16
// X_low pack and chunk-mean, exactly as the old scalar dft did.
__global__ __launch_bounds__(256) void dft_mfma(
    const float* __restrict__ X, const bf16_t* __restrict__ dhi,
    const bf16_t* __restrict__ dres, bf16_t* __restrict__ Xh,
    bf16_t* __restrict__ XLr, bf16_t* __restrict__ XLi,
    bf16_t* __restrict__ gmean) {
  const int bc = blockIdx.y;        // 0..255
  const int d0 = blockIdx.x * 256;  // 4 d-tiles
  const int tid = threadIdx.x;
  const int lane = tid & 63, wave = tid >> 6;
  const int mr = lane & 15, q = lane >> 4;
  const int wn = wave * 64;

  __shared__ bf16_t Ahi[80 * 64];
  __shared__ bf16_t Ares[80 * 64];
  __shared__ bf16_t Bh[256 * 64];
  __shared__ bf16_t Br[256 * 64];

  // basis: 5120 elems = 10 chunks of 512; wave-uniform LDS bases
  for (int i = wave; i < 10; i += 4) {
    gld_lds16(dhi + (i * 64 + lane) * 8, Ahi + i * 512);
    gld_lds16(dres + (i * 64 + lane) * 8, Ares + i * 512);
  }

  // B transpose-stage: thread owns d-col (d0+tid); 64 coalesced fp32 loads,
  // split hi/res, ds_write_b128 with XOR slot swizzle (g ^ (tid&7)).
  {
    const float* xc = X + ((long)bc * 64) * 1024 + d0 + tid;
    const int sw = tid & 7;
#pragma unroll
    for (int g = 0; g < 8; g++) {
      bf16x8 vh, vr;
#pragma unroll
      for (int i = 0; i < 8; i++) {
        float v = xc[(long)(g * 8 + i) * 1024];
        bf16_t h = (bf16_t)v;
        vh[i] = h;
        vr[i] = (bf16_t)(v - (float)h);
      }
      *(bf16x8*)&Bh[tid * 64 + ((g ^ sw) << 3)] = vh;
      *(bf16x8*)&Br[tid * 64 + ((g ^ sw) << 3)] = vr;
    }
  }
  __syncthreads();  // drains vmcnt (basis) + lgkm (B writes)

  f32x4 acc[5][4];
#pragma unroll
  for (int i = 0; i < 5; i++)
#pragma unroll
    for (int j = 0; j < 4; j++) acc[i][j] = (f32x4){0.f, 0.f, 0.f, 0.f};

#pragma unroll
  for (int s = 0; s < 2; s++) {
    bf16x8 bh[4], br[4];
#pragma unroll
    for (int ni = 0; ni < 4; ni++) {
      int dcol = wn + ni * 16 + mr;
      int so = (((s * 4 + q) ^ (dcol & 7)) << 3);
      bh[ni] = *(const bf16x8*)&Bh[dcol * 64 + so];
      br[ni] = *(const bf16x8*)&Br[dcol * 64 + so];
    }
#pragma unroll
    for (int mi = 0; mi < 5; mi++) {
      int trow = mi * 16 + mr;
      int so = (((s * 4 + q) ^ (trow & 7)) << 3);
      bf16x8 ah = *(const bf16x8*)&Ahi[trow * 64 + so];
      bf16x8 ar = *(const bf16x8*)&Ares[trow * 64 + so];
#pragma unroll
      for (int ni = 0; ni < 4; ni++) {
        acc[mi][ni] = __builtin_amdgcn_mfma_f32_16x16x32_bf16(
            ah, bh[ni], acc[mi][ni], 0, 0, 0);
        acc[mi][ni] = __builtin_amdgcn_mfma_f32_16x16x32_bf16(
            ah, br[ni], acc[mi][ni], 0, 0, 0);
        acc[mi][ni] = __builtin_amdgcn_mfma_f32_16x16x32_bf16(
            ar, bh[ni], acc[mi][ni], 0, 0, 0);
      }
    }
  }

  const int b = bc >> 6, ch = bc & 63;
  bf16_t* xp = Xh + (long)bc * 66 * 1024 + d0;
#pragma unroll
  for (int mi = 0; mi < 5; mi++) {
#pragma unroll
    for (int r = 0; r < 4; r++) {
      int row = mi * 16 + q * 4 + r;
      if (row >= 66) continue;
#pragma unroll
      for (int ni = 0; ni < 4; ni++) {
        int col = wn + ni * 16 + mr;
        float val = acc[mi][ni][r];
        xp[(long)row * 1024 + col] = (bf16_t)val;
        if (row == 0)
          gmean[(long)bc * 1024 + d0 + col] = (bf16_t)(val * (1.f / 64.f));
        if (row < 4)
          XLr[((long)(b * 256 + ch * 4 + row)) * 1024 + d0 + col] = (bf16_t)val;
        if (row >= 33 && row < 37)
          XLi[((long)(b * 256 + ch * 4 + row - 33)) * 1024 + d0 + col] =
              (bf16_t)val;
      }
    }
  }
}

// ============================ bf16 MFMA GEMM ===============================
// C[M,N] = A[M,K] @ B[N,K]^T. 128x128 tile, BK=32, 2x2 waves x 4x4 mfma,
// global_load_lds(16B) staging into unpadded [row][k] LDS (m97 structure).
// Used for the small-M GEMMs (QKV / gate / O-proj).
template <int EMODE>
__global__ __launch_bounds__(256) void mmbf_kernel(
    const bf16_t* __restrict__ A0, const bf16_t* __restrict__ A1,
    const bf16_t* __restrict__ B0, const bf16_t* __restrict__ B1,
    int N, int K,
    void* __restrict__ C0v, void* __restrict__ C1v,
    const bf16_t* __restrict__ E0, const bf16_t* __restrict__ E1,
    bf16_t* __restrict__ XhMut,
    const float* __restrict__ gate, const float* __restrict__ alpha_ptr) {
  constexpr int BM = 128, BN = 128, BK = 32;  // no pad: lane-order layout
  __shared__ bf16_t As[BM * BK];
  __shared__ bf16_t Bs[BN * BK];
  const int z = blockIdx.z;
  const bf16_t* A = z ? A1 : A0;
  const bf16_t* B = z ? B1 : B0;
  void* Cv = z ? C1v : C0v;
  const bf16_t* E = z ? E1 : E0;
  const int imoff = z ? 33 * 1024 : 0;
  const int tid = threadIdx.x;
  const int lane = tid & 63;
  const int wave = tid >> 6;
  const int wm = (wave & 1) * 64, wn = (wave >> 1) * 64;
  const int m0 = blockIdx.x * BM, n0 = blockIdx.y * BN;
  const int q = lane >> 4, mr = lane & 15;
  // staging: lane -> (row within 16-row wave group, 8-elem k group)
  const int lrow = lane >> 2, lk8 = (lane & 3) * 8;

  f32x4 acc[4][4];
#pragma unroll
  for (int i = 0; i < 4; i++)
#pragma unroll
    for (int j = 0; j < 4; j++) acc[i][j] = (f32x4){0.f, 0.f, 0.f, 0.f};

  const long arow0 = (long)(m0 + wave * 16 + lrow) * K + lk8;
  const long brow0 = (long)(n0 + wave * 16 + lrow) * K + lk8;

  for (int kb = 0; kb < K; kb += BK) {
#pragma unroll
    for (int it = 0; it < 2; it++) {
      // wave w stages rows [w*16 + it*64, +16); LDS base wave-uniform
      gld_lds16(A + arow0 + (long)it * 64 * K + kb, As + (wave * 16 + it * 64) * BK);
      gld_lds16(B + brow0 + (long)it * 64 * K + kb, Bs + (wave * 16 + it * 64) * BK);
    }
    __syncthreads();  // drains vmcnt(0) -> LDS tiles complete
    bf16x8 af[4], bfr[4];
#pragma unroll
    for (int mi = 0; mi < 4; mi++)
      af[mi] = *(const bf16x8*)&As[(wm + mi * 16 + mr) * BK + q * 8];
#pragma unroll
    for (int ni = 0; ni < 4; ni++)
      bfr[ni] = *(const bf16x8*)&Bs[(wn + ni * 16 + mr) * BK + q * 8];
#pragma unroll
    for (int mi = 0; mi < 4; mi++)
#pragma unroll
      for (int ni = 0; ni < 4; ni++)
        acc[mi][ni] = __builtin_amdgcn_mfma_f32_16x16x32_bf16(
            af[mi], bfr[ni], acc[mi][ni], 0, 0, 0);
    __syncthreads();  // LDS reads done before next stage overwrites
  }

  float alpha = 0.f;
  if constexpr (EMODE == EP_FUSELOW) alpha = 1.f / (1.f + __expf(-alpha_ptr[0]));
#pragma unroll
  for (int mi = 0; mi < 4; mi++) {
#pragma unroll
    for (int ni = 0; ni < 4; ni++) {
      int col = n0 + wn + ni * 16 + mr;
      int rbase = m0 + wm + mi * 16 + q * 4;
#pragma unroll
      for (int r = 0; r < 4; r++) {
        int row = rbase + r;
        float val = acc[mi][ni][r];
        if constexpr (EMODE == EP_NONE) {
          ((bf16_t*)Cv)[(long)row * N + col] = (bf16_t)val;
        } else if constexpr (EMODE == EP_SIGMOID) {
          ((float*)Cv)[(long)row * N + col] = 1.f / (1.f + __expf(-val));
        } else if constexpr (EMODE == EP_FUSELOW) {
          // E = contiguous bf16 X_low pack, same row/col indexing as C
          float xl = (float)E[(long)row * 1024 + col];
          ((float*)Cv)[(long)row * 1024 + col] = alpha * val + (1.f - alpha) * xl;
        } else {  // EP_HIGH: in-place A_high = val*g + X_high (Xh bf16)
          int bc = row / 29, l = row - bc * 29;
          long x = ((long)bc * 66 + 4 + l) * 1024 + imoff + col;
          XhMut[x] = (bf16_t)fmaf(val, gate[(long)bc * 1024 + col], (float)XhMut[x]);
        }
      }
    }
  }
}

// ================= 256^2-tile pipelined GEMM for EP_HIGH ===================
// C[7424,1024] = A[7424,1024] @ B[1024,1024]^T, epilogue: Xh high rows
// += C*gate (in place). 512 threads = 8 waves (2M x 4N), per-wave 128x64 out.
// BK=32, LDS ring of 4 slots, depth-3 prefetch with counted vmcnt.
// Round 7: swizzle sigma(r) = ((r&3)+((r>>2)&3))&3 via pre-swizzled GLOBAL
// source (linear LDS dest, rule #21) — separates rows mr,mr+4,mr+8,mr+12
// that previously shared slot AND bank window (the measured 4-way residue).
__global__ __launch_bounds__(512, 2) void gemm256_high(
    const bf16_t* __restrict__ A0, const bf16_t* __restrict__ A1,
    const bf16_t* __restrict__ B0, const bf16_t* __restrict__ B1,
    bf16_t* __restrict__ XhMut, const float* __restrict__ gate) {
  constexpr int K = 1024;
  constexpr int NT = K / 32;  // 32 K-tiles
  __shared__ bf16_t lds[4][2][256 * 32];  // [ring][A|B][row*32+k] = 128 KiB

  // block-id swizzle: XCD = id%8 gets ~4 consecutive m-panels with all their
  // (n,z) tiles -> A panels stay L2-resident per XCD.
  const int id = blockIdx.x;                 // 232 blocks
  const int kk = (id & 7) * 29 + (id >> 3);  // bijection [0,232)
  const int mt = kk >> 3, rem = kk & 7;
  const int nt = rem & 3, z = rem >> 2;
  const bf16_t* A = z ? A1 : A0;
  const bf16_t* B = z ? B1 : B0;
  const int imoff = z ? 33 * 1024 : 0;
  const int m0 = mt * 256, n0 = nt * 256;

  const int tid = threadIdx.x;
  const int lane = tid & 63, wave = tid >> 6;
  const int wm = (wave & 1) * 128, wn = (wave >> 1) * 64;
  const int q = lane >> 4, mr = lane & 15;
  // staging: chunk covers row tid>>2; fetched global 16B-slot is
  // (tid&3) ^ sigma(row) so LDS[row][c] = G[row][c ^ sigma(row)]
  const int srow = tid >> 2;
  const int gk8 = (((tid & 3) ^ ((((tid >> 2) & 3) + ((tid >> 4) & 3)) & 3)) << 3);

  f32x4 acc[8][4];
#pragma unroll
  for (int i = 0; i < 8; i++)
#pragma unroll
    for (int j = 0; j < 4; j++) acc[i][j] = (f32x4){0.f, 0.f, 0.f, 0.f};

  // stage K-tile t into ring slot t&3: 4 x gld_lds16 per thread (2 A + 2 B)
  auto stage = [&](int t) {
    const int bi = t & 3;
    const int kb = t * 32;
#pragma unroll
    for (int rd = 0; rd < 2; rd++) {
      gld_lds16(A + (long)(m0 + rd * 128 + srow) * K + kb + gk8,
                &lds[bi][0][(rd * 512 + wave * 64) * 8]);
      gld_lds16(B + (long)(n0 + rd * 128 + srow) * K + kb + gk8,
                &lds[bi][1][(rd * 512 + wave * 64) * 8]);
    }
  };

  stage(0);
  stage(1);
  stage(2);

  // swizzled 8-elem k-slot for fragment reads: q ^ sigma(row); sigma depends
  // only on mr (wm, mi*16, wn, ni*16 are multiples of 16)
  const int asl = (q ^ (((mr & 3) + ((mr >> 2) & 3)) & 3)) * 8;

  for (int t = 0; t < NT; t++) {
    // tile t landed; tiles t+1,t+2 (8 loads/thread) remain in flight.
    if (t < NT - 2)
      asm volatile("s_waitcnt vmcnt(8)" ::: "memory");
    else if (t == NT - 2)
      asm volatile("s_waitcnt vmcnt(4)" ::: "memory");
    else
      asm volatile("s_waitcnt vmcnt(0)" ::: "memory");
    __builtin_amdgcn_sched_barrier(0);
    __builtin_amdgcn_s_barrier();  // all waves' tile-t LDS writes now visible
    if (t + 3 < NT) stage(t + 3);  // slot freed before this barrier

    const bf16_t* As_ = &lds[t & 3][0][0];
    const bf16_t* Bs_ = &lds[t & 3][1][0];
    bf16x8 bfr[4];
#pragma unroll
    for (int ni = 0; ni < 4; ni++)
      bfr[ni] = *(const bf16x8*)&Bs_[(wn + ni * 16 + mr) * 32 + asl];
    __builtin_amdgcn_s_setprio(1);
#pragma unroll
    for (int mi = 0; mi < 8; mi++) {
      bf16x8 af = *(const bf16x8*)&As_[(wm + mi * 16 + mr) * 32 + asl];
#pragma unroll
      for (int ni = 0; ni < 4; ni++)
        acc[mi][ni] = __builtin_amdgcn_mfma_f32_16x16x32_bf16(
            af, bfr[ni], acc[mi][ni], 0, 0, 0);
    }
    __builtin_amdgcn_s_setprio(0);
  }

  // epilogue: Xh[bc][4+l][:] += C * gate[bc][:]  (rows: row = bc*29 + l)
#pragma unroll
  for (int mi = 0; mi < 8; mi++) {
#pragma unroll
    for (int r = 0; r < 4; r++) {
      int row = m0 + wm + mi * 16 + q * 4 + r;
      int bc = row / 29, l = row - bc * 29;
      long xbase = ((long)bc * 66 + 4 + l) * 1024 + imoff;
      const float* gp = gate + (long)bc * 1024;
#pragma unroll
      for (int ni = 0; ni < 4; ni++) {
        int col = n0 + wn + ni * 16 + mr;
        long x = xbase + col;
        XhMut[x] = (bf16_t)fmaf(acc[mi][ni][r], gp[col], (float)XhMut[x]);
      }
    }
  }
}

// ====================== MFMA flash attention ===============================
// grid (NH=16, B*4 qtiles=16, 2). block 256 = 4 waves; wave w owns q rows
// [qt*64 + w*16, +16). Block-causal (chunk=4): kt<qt visible, kt==qt masked.
__global__ __launch_bounds__(256) void attn_mfma(const bf16_t* __restrict__ QKVr,
                                                 const bf16_t* __restrict__ QKVi,
                                                 bf16_t* __restrict__ Or_,
                                                 bf16_t* __restrict__ Oi_) {
  const int h = blockIdx.x;
  const int b = blockIdx.y >> 2, qt = blockIdx.y & 3;
  const bf16_t* QKV = blockIdx.z ? QKVi : QKVr;
  bf16_t* O = blockIdx.z ? Oi_ : Or_;
  const int kvh = h >> 2;
  const int tid = threadIdx.x;
  const int lane = tid & 63, wave = tid >> 6;
  const int mr = lane & 15, q4 = lane >> 4;

  __shared__ bf16_t Ks[64 * 72];
  __shared__ bf16_t Vt[64 * 72];
  __shared__ bf16_t Ps[4][16 * 72];

  bf16x8 af[2];
  {
    const bf16_t* qp =
        QKV + (long)(b * 256 + qt * 64 + wave * 16 + mr) * 1536 + h * 64;
    af[0] = *(const bf16x8*)(qp + q4 * 8);
    af[1] = *(const bf16x8*)(qp + 32 + q4 * 8);
  }
  f32x4 Oacc[4];
#pragma unroll
  for (int ni = 0; ni < 4; ni++) Oacc[ni] = (f32x4){0.f, 0.f, 0.f, 0.f};
  float mrow[4], lrow[4];
#pragma unroll
  for (int r = 0; r < 4; r++) { mrow[r] = -1e30f; lrow[r] = 0.f; }

  for (int kt = 0; kt <= qt; kt++) {
#pragma unroll
    for (int it = 0; it < 2; it++) {
      int idx = tid + it * 256;
      int key = idx >> 3, dg = idx & 7;
      const bf16_t* kp = QKV + (long)(b * 256 + kt * 64 + key) * 1536 + 1024 +
                         kvh * 64 + dg * 8;
      *(bf16x8*)&Ks[key * 72 + dg * 8] = *(const bf16x8*)kp;
      bf16x8 vv = *(const bf16x8*)(kp + 256);
#pragma unroll
      for (int j = 0; j < 8; j++) Vt[(dg * 8 + j) * 72 + key] = vv[j];
    }
    __syncthreads();

    f32x4 S[4];
#pragma unroll
    for (int ni = 0; ni < 4; ni++) {
      S[ni] = (f32x4){0.f, 0.f, 0.f, 0.f};
#pragma unroll
      for (int s = 0; s < 2; s++) {
        bf16x8 kb = *(const bf16x8*)&Ks[(ni * 16 + mr) * 72 + s * 32 + q4 * 8];
        S[ni] = __builtin_amdgcn_mfma_f32_16x16x32_bf16(af[s], kb, S[ni], 0, 0, 0);
      }
    }
#pragma unroll
    for (int ni = 0; ni < 4; ni++) {
#pragma unroll
      for (int r = 0; r < 4; r++) {
        float v = S[ni][r] * 0.125f;
        if (kt == qt) {
          int qrow = wave * 16 + q4 * 4 + r;
          int kcol = ni * 16 + mr;
          if ((qrow >> 2) < (kcol >> 2)) v = -1e30f;
        }
        S[ni][r] = v;
      }
    }
#pragma unroll
    for (int r = 0; r < 4; r++) {
      float mx = fmaxf(fmaxf(S[0][r], S[1][r]), fmaxf(S[2][r], S[3][r]));
#pragma unroll
      for (int off = 1; off < 16; off <<= 1) mx = fmaxf(mx, __shfl_xor(mx, off));
      float mn = fmaxf(mrow[r], mx);
      float sc = __expf(mrow[r] - mn);
      mrow[r] = mn;
      float rs = 0.f;
#pragma unroll
      for (int ni = 0; ni < 4; ni++) {
        float p = __expf(S[ni][r] - mn);
        rs += p;
        Ps[wave][(q4 * 4 + r) * 72 + ni * 16 + mr] = (bf16_t)p;
      }
#pragma unroll
      for (int off = 1; off < 16; off <<= 1) rs += __shfl_xor(rs, off);
      lrow[r] = lrow[r] * sc + rs;
#pragma unroll
      for (int ni = 0; ni < 4; ni++) Oacc[ni][r] *= sc;
    }
    bf16x8 pa[2];
    pa[0] = *(const bf16x8*)&Ps[wave][mr * 72 + q4 * 8];
    pa[1] = *(const bf16x8*)&Ps[wave][mr * 72 + 32 + q4 * 8];
#pragma unroll
    for (int ni = 0; ni < 4; ni++) {
#pragma unroll
      for (int s = 0; s < 2; s++) {
        bf16x8 vb = *(const bf16x8*)&Vt[(ni * 16 + mr) * 72 + s * 32 + q4 * 8];
        Oacc[ni] = __builtin_amdgcn_mfma_f32_16x16x32_bf16(pa[s], vb, Oacc[ni], 0, 0, 0);
      }
    }
    __syncthreads();
  }

#pragma unroll
  for (int r = 0; r < 4; r++) {
    float inv = 1.f / lrow[r];
    long row = b * 256 + qt * 64 + wave * 16 + q4 * 4 + r;
#pragma unroll
    for (int ni = 0; ni < 4; ni++)
      O[row * 1024 + h * 64 + ni * 16 + mr] = (bf16_t)(Oacc[ni][r] * inv);
  }
}

// ===================== depthwise causal conv + GELU ========================
__global__ __launch_bounds__(256) void dwconv_kernel(const bf16_t* __restrict__ Xh,
                                                     const float* __restrict__ dwr,
                                                     const float* __restrict__ dwi,
                                                     bf16_t* __restrict__ Gr,
                                                     bf16_t* __restrict__ Gi) {
  const int d = blockIdx.x * 256 + threadIdx.x;
  const int bc = blockIdx.y;
  const float* dw = blockIdx.z ? dwi : dwr;
  bf16_t* G = blockIdx.z ? Gi : Gr;
  const int imoff = blockIdx.z ? 33 * 1024 : 0;
  float w[7];
#pragma unroll
  for (int j = 0; j < 7; j++) w[j] = dw[d * 7 + j];
  float x[29];
#pragma unroll
  for (int l = 0; l < 29; l++)
    x[l] = (float)Xh[((long)bc * 66 + 4 + l) * 1024 + imoff + d];
#pragma unroll
  for (int l = 0; l < 29; l++) {
    float y = 0.f;
#pragma unroll
    for (int j = 0; j < 7; j++) {
      int src = l - 6 + j;
      if (src >= 0) y = fmaf(w[j], x[src], y);
    }
    float ge = 0.5f * y * (1.f + erff(y * 0.7071067811865475f));
    G[((long)bc * 29 + l) * 1024 + d] = (bf16_t)ge;
  }
}

// ======================= irfft via MFMA + fp32 low =========================
// out[bc*64+t][d] = sum_k T[t][k]*XhHigh[bc][k][d]  (MFMA, basis hi+res bf16)
//                 + fp32 low-bin part from Af (f=0..3) via Tlow.
__global__ __launch_bounds__(256) void irfft_mfma(
    const bf16_t* __restrict__ Xh, const float* __restrict__ Afr,
    const float* __restrict__ Afi, const bf16_t* __restrict__ bhi,
    const bf16_t* __restrict__ bres, const float* __restrict__ tlow,
    float* __restrict__ out) {
  const int bc = blockIdx.y;        // 0..255
  const int d0 = blockIdx.x * 256;  // 4 d-tiles
  const int tid = threadIdx.x;
  const int lane = tid & 63, wave = tid >> 6;
  const int mr = lane & 15, q = lane >> 4;
  const int wn = wave * 64;

  __shared__ bf16_t Ahi[64 * 64];
  __shared__ bf16_t Ares[64 * 64];
  __shared__ bf16_t Bs[256 * 64];
  __shared__ float Tl[64 * 8];

  // basis tables: linear gld_lds (already pre-swizzled in global)
  gld_lds16(bhi + (wave * 64 + lane) * 8, Ahi + wave * 64 * 8);
  gld_lds16(bhi + (256 + wave * 64 + lane) * 8, Ahi + (256 + wave * 64) * 8);
  gld_lds16(bres + (wave * 64 + lane) * 8, Ares + wave * 64 * 8);
  gld_lds16(bres + (256 + wave * 64 + lane) * 8, Ares + (256 + wave * 64) * 8);
  if (tid < 128) ((float4*)Tl)[tid] = ((const float4*)tlow)[tid];

  // B transpose-stage: thread owns d-column (d0+tid); rows k=0..56 map to
  // Xh rows 4..32 (real f=4..32) and 37..64 (imag f=4..31); 57..63 zero.
  {
    const bf16_t* xc = Xh + (long)bc * 66 * 1024 + d0 + tid;
    const int sw = tid & 7;
#pragma unroll
    for (int g = 0; g < 8; g++) {
      bf16x8 v;
#pragma unroll
      for (int i = 0; i < 8; i++) {
        int j = g * 8 + i;
        int row = (j < 29) ? (4 + j) : (8 + j);
        v[i] = (j < 57) ? xc[(long)row * 1024] : (bf16_t)0.f;
      }
      *(bf16x8*)&Bs[tid * 64 + ((g ^ sw) << 3)] = v;
    }
  }
  __syncthreads();  // drains vmcnt -> basis complete; ds_writes complete

  f32x4 acc[4][4];
#pragma unroll
  for (int i = 0; i < 4; i++)
#pragma unroll
    for (int j = 0; j < 4; j++) acc[i][j] = (f32x4){0.f, 0.f, 0.f, 0.f};

#pragma unroll
  for (int s = 0; s < 2; s++) {
    bf16x8 bfv[4];
#pragma unroll
    for (int ni = 0; ni < 4; ni++) {
      int dcol = wn + ni * 16 + mr;
      bfv[ni] = *(const bf16x8*)&Bs[dcol * 64 + (((s * 4 + q) ^ (dcol & 7)) << 3)];
    }
#pragma unroll
    for (int mi = 0; mi < 4; mi++) {
      int trow = mi * 16 + mr;
      int so = (((s * 4 + q) ^ (trow & 7)) << 3);
      bf16x8 ah = *(const bf16x8*)&Ahi[trow * 64 + so];
      bf16x8 ar = *(const bf16x8*)&Ares[trow * 64 + so];
#pragma unroll
      for (int ni = 0; ni < 4; ni++) {
        acc[mi][ni] = __builtin_amdgcn_mfma_f32_16x16x32_bf16(
            ah, bfv[ni], acc[mi][ni], 0, 0, 0);
        acc[mi][ni] = __builtin_amdgcn_mfma_f32_16x16x32_bf16(
            ar, bfv[ni], acc[mi][ni], 0, 0, 0);
      }
    }
  }

  // fp32 low-bin epilogue: rows f=0..3 of Af (alpha-fused), Tlow basis
  const int arow = (bc >> 6) * 256 + (bc & 63) * 4;
  float R[4][7];
#pragma unroll
  for (int ni = 0; ni < 4; ni++) {
    long ab = (long)arow * 1024 + d0 + wn + ni * 16 + mr;
    R[ni][0] = Afr[ab];
    R[ni][1] = Afr[ab + 1024];
    R[ni][2] = Afi[ab + 1024];
    R[ni][3] = Afr[ab + 2048];
    R[ni][4] = Afi[ab + 2048];
    R[ni][5] = Afr[ab + 3072];
    R[ni][6] = Afi[ab + 3072];
  }
  const long obase = ((long)bc * 64) * 1024 + d0;
#pragma unroll
  for (int mi = 0; mi < 4; mi++) {
#pragma unroll
    for (int r = 0; r < 4; r++) {
      int t = mi * 16 + q * 4 + r;
      const float* tl = &Tl[t * 8];
#pragma unroll
      for (int ni = 0; ni < 4; ni++) {
        float low = tl[0] * R[ni][0];
        low = fmaf(tl[1], R[ni][1], low);
        low = fmaf(tl[2], R[ni][2], low);
        low = fmaf(tl[3], R[ni][3], low);
        low = fmaf(tl[4], R[ni][4], low);
        low = fmaf(tl[5], R[ni][5], low);
        low = fmaf(tl[6], R[ni][6], low);
        out[obase + (long)t * 1024 + wn + ni * 16 + mr] = acc[mi][ni][r] + low;
      }
    }
  }
}

// ============================ launcher =====================================
extern "C" void kernel_launch(void* const* d_in, const int* in_sizes, int n_in,
                              void* d_out, int out_size, void* d_ws, size_t ws_size,
                              hipStream_t stream) {
  const float* hidden = (const float*)d_in[0];
  const float* q_w = (const float*)d_in[1];
  const float* k_w = (const float*)d_in[2];
  const float* v_w = (const float*)d_in[3];
  const float* o_w = (const float*)d_in[4];
  const float* dw_r = (const float*)d_in[5];
  const float* pw_r = (const float*)d_in[6];
  const float* dw_i = (const float*)d_in[7];
  const float* pw_i = (const float*)d_in[8];
  const float* gate_w = (const float*)d_in[9];
  const float* alpha_raw = (const float*)d_in[10];
  float* out = (float*)d_out;

  float* ws = (float*)d_ws;
  // fp32 region
  float* Afr = ws;                       // 1024*1024
  float* Afi = Afr + 1048576;
  float* gg = Afi + 1048576;             // 256*1024
  // bf16 region
  bf16_t* bws = (bf16_t*)(gg + 262144);
  bf16_t* Xh = bws;                      // 256*66*1024 = 17,301,504 bf16
  bf16_t* Wqkv_b = Xh + 17301504;        // 1536*1024
  bf16_t* ow_b = Wqkv_b + 1572864;       // 1024*1024
  bf16_t* gw_b = ow_b + 1048576;
  bf16_t* pwr_b = gw_b + 1048576;
  bf16_t* pwi_b = pwr_b + 1048576;
  bf16_t* XLr = pwi_b + 1048576;         // 1024*1024
  bf16_t* XLi = XLr + 1048576;
  bf16_t* gmean = XLi + 1048576;         // 256*1024
  bf16_t* QKVbr = gmean + 262144;        // 1024*1536
  bf16_t* QKVbi = QKVbr + 1572864;
  bf16_t* Obr = QKVbi + 1572864;         // 1024*1024
  bf16_t* Obi = Obr + 1048576;
  bf16_t* Gr = Obi + 1048576;            // 7424*1024
  bf16_t* Gi = Gr + 7602176;
  bf16_t* bhi = Gi + 7602176;            // 64*64 irfft basis hi
  bf16_t* bres = bhi + 4096;             // 64*64 irfft basis residual
  bf16_t* dbhi = bres + 4096;            // 80*64 dft basis hi
  bf16_t* dbres = dbhi + 5120;           // 80*64 dft basis residual
  float* tlowp = (float*)(dbres + 5120); // 64*8 fp32

  // 0) basis tables (pre-swizzled)
  mk_basis<<<38, 256, 0, stream>>>(dbhi, dbres, bhi, bres, tlowp);
  // 1) rfft via MFMA -> bf16 Xh + bf16 X_low pack + bf16 chunk-mean
  dft_mfma<<<dim3(4, 256), 256, 0, stream>>>(hidden, dbhi, dbres, Xh, XLr,
                                             XLi, gmean);
  // 2) weights -> bf16
  concat_w<<<1536, 256, 0, stream>>>(q_w, k_w, v_w, Wqkv_b);
  cvt4_bf16<<<dim3(1024, 4), 256, 0, stream>>>(o_w, gate_w, pw_r, pw_i,
                                               ow_b, gw_b, pwr_b, pwi_b);
  // 3) QKV projections (real & imag via z), bf16 out
  mmbf_kernel<EP_NONE><<<dim3(8, 12, 2), 256, 0, stream>>>(
      XLr, XLi, Wqkv_b, Wqkv_b, 1536, 1024, QKVbr, QKVbi, nullptr, nullptr,
      nullptr, nullptr, nullptr);
  // 4) gate = sigmoid(mean @ gate_w^T)  (gmean already /64)
  mmbf_kernel<EP_SIGMOID><<<dim3(2, 8, 1), 256, 0, stream>>>(
      gmean, gmean, gw_b, gw_b, 1024, 1024, gg, gg, nullptr, nullptr,
      nullptr, nullptr, nullptr);
  // 5) MFMA flash attention (real & imag), bf16 O out
  attn_mfma<<<dim3(16, 16, 2), 256, 0, stream>>>(QKVbr, QKVbi, Obr, Obi);
  // 6) O projection + alpha*A_low + (1-alpha)*X_low -> fp32 Af
  mmbf_kernel<EP_FUSELOW><<<dim3(8, 8, 2), 256, 0, stream>>>(
      Obr, Obi, ow_b, ow_b, 1024, 1024, Afr, Afi, XLr, XLi,
      nullptr, nullptr, alpha_raw);
  // 7) depthwise causal conv + exact GELU on high bins, bf16 out
  dwconv_kernel<<<dim3(4, 256, 2), 256, 0, stream>>>(Xh, dw_r, dw_i, Gr, Gi);
  // 8) pointwise conv + gate + residual, in-place into bf16 Xh high rows
  gemm256_high<<<dim3(232), 512, 0, stream>>>(Gr, Gi, pwr_b, pwi_b, Xh, gg);
  // 9) irfft via MFMA + fp32 low-bin epilogue
  irfft_mfma<<<dim3(4, 256), 256, 0, stream>>>(Xh, Afr, Afi, bhi, bres,
                                               tlowp, out);
}

// Round 5
// 317.837 us; speedup vs baseline: 1.2791x; 1.0811x over previous
//
#include <hip/hip_runtime.h>
#include <math.h>

// ---------------------------------------------------------------------------
// CausalHFPLayer: B=4, N=4096, D=1024, C=64 -> nc=64 chunks/batch, BC=256
// rfft bins M=33, k_low=4, high bins 29. NH=16, NKV=4, HD=64, T=256.
// Round 9 (= R8 resubmit; R8 bench died to container-infra failure, source
// audited clean): occupancy pass. All GEMMs -> gemm128<EMODE>: 128^2 tile,
// 4-slot counted-vmcnt ring, 64KB LDS, 2 blocks/CU. dft/irfft MFMA kernels
// shrunk to 128-col blocks (52/34KB LDS -> 3-4 blocks/CU). concat+cvt4
// merged into one prep_w launch.
// ---------------------------------------------------------------------------

typedef __bf16 bf16_t;
typedef bf16_t bf16x8 __attribute__((ext_vector_type(8)));
typedef float f32x4 __attribute__((ext_vector_type(4)));

#define EP_NONE 0
#define EP_SIGMOID 1
#define EP_FUSELOW 2
#define EP_HIGH 3

// async global->LDS 16B copy. LDS dest is wave-uniform base + lane*16, so the
// lds pointer must be identical across the wave's lanes (m104/m108).
__device__ __forceinline__ void gld_lds16(const bf16_t* g, bf16_t* l) {
  __builtin_amdgcn_global_load_lds(
      (const __attribute__((address_space(1))) unsigned int*)g,
      (__attribute__((address_space(3))) unsigned int*)l, 16, 0, 0);
}

// =============== weight prep: concat qkv + 4x fp32->bf16 ===================
// one kernel, 5632 blocks: float4 index gi < 393216 -> qkv concat; else the
// 4 square matrices (o_w, gate_w, pw_r, pw_i), 262144 float4 each.
__global__ __launch_bounds__(256) void prep_w(
    const float* __restrict__ qw, const float* __restrict__ kw,
    const float* __restrict__ vw, const float* __restrict__ ow,
    const float* __restrict__ gw, const float* __restrict__ pwr,
    const float* __restrict__ pwi, bf16_t* __restrict__ Wqkv,
    bf16_t* __restrict__ owb, bf16_t* __restrict__ gwb,
    bf16_t* __restrict__ pwrb, bf16_t* __restrict__ pwib) {
  int gi = blockIdx.x * 256 + threadIdx.x;
  float4 v;
  bf16_t* o;
  if (gi < 393216) {
    if (gi < 262144) v = ((const float4*)qw)[gi];
    else if (gi < 327680) v = ((const float4*)kw)[gi - 262144];
    else v = ((const float4*)vw)[gi - 327680];
    o = Wqkv + (long)gi * 4;
  } else {
    int j = gi - 393216;
    int sel = j >> 18, off = j & 262143;
    const float* s = sel == 0 ? ow : sel == 1 ? gw : sel == 2 ? pwr : pwi;
    bf16_t* d = sel == 0 ? owb : sel == 1 ? gwb : sel == 2 ? pwrb : pwib;
    v = ((const float4*)s)[off];
    o = d + (long)off * 4;
  }
  o[0] = (bf16_t)v.x; o[1] = (bf16_t)v.y; o[2] = (bf16_t)v.z; o[3] = (bf16_t)v.w;
}

// ====================== fft basis tables (constant) ========================
// dft basis D[80 r][64 k]: r<33: cos(2*pi*r*k/64); 33..65: -sin(...); 66..79
// zero. Pre-swizzled: (r,k) at r*64 + ((k>>3)^(r&7))*8 + (k&7). bf16 hi+res.
// irfft basis T[64 t][64 k] (k: 0..28 Rf f=4..32; 29..56 If f=4..31; pad),
// same swizzle/split. Tlow[64][8] fp32 low-bin basis.
__global__ __launch_bounds__(256) void mk_basis(bf16_t* __restrict__ dhi,
                                                bf16_t* __restrict__ dres,
                                                bf16_t* __restrict__ bhi,
                                                bf16_t* __restrict__ bres,
                                                float* __restrict__ tlow) {
  int idx = blockIdx.x * 256 + threadIdx.x;
  const float TW = 6.283185307179586f / 64.f;
  if (idx < 5120) {  // dft basis
    int r = idx >> 6, k = idx & 63;
    float v = 0.f;
    if (r < 33) {
      v = cosf(TW * (float)((r * k) & 63));
    } else if (r < 66) {
      v = -sinf(TW * (float)(((r - 33) * k) & 63));
    }
    bf16_t h = (bf16_t)v;
    float res = v - (float)h;
    int addr = r * 64 + (((k >> 3) ^ (r & 7)) << 3) + (k & 7);
    dhi[addr] = h;
    dres[addr] = (bf16_t)res;
  } else if (idx < 9216) {  // irfft basis
    int i = idx - 5120;
    int t = i >> 6, k = i & 63;
    float v = 0.f;
    if (k < 28) {
      int ft = ((4 + k) * t) & 63;
      v = 2.f * cosf(TW * (float)ft) * (1.f / 64.f);
    } else if (k == 28) {  // f=32 Nyquist: single-counted
      int ft = (32 * t) & 63;
      v = cosf(TW * (float)ft) * (1.f / 64.f);
    } else if (k < 57) {
      int ft = ((k - 25) * t) & 63;
      v = -2.f * sinf(TW * (float)ft) * (1.f / 64.f);
    }
    bf16_t h = (bf16_t)v;
    float res = v - (float)h;
    int addr = t * 64 + (((k >> 3) ^ (t & 7)) << 3) + (k & 7);
    bhi[addr] = h;
    bres[addr] = (bf16_t)res;
  } else if (idx < 9728) {  // tlow
    int i = idx - 9216;
    int t = i >> 3, j = i & 7;
    float v = 0.f;
    if (j == 0) v = 1.f / 64.f;
    else if (j < 7) {
      int f = (j + 1) >> 1;  // 1,1,2,2,3,3
      int ft = (f * t) & 63;
      float th = TW * (float)ft;
      v = (j & 1) ? 2.f * cosf(th) * (1.f / 64.f)
                  : -2.f * sinf(th) * (1.f / 64.f);
    }
    tlow[i] = v;
  }
}

// ========================= DFT (rfft) via MFMA =============================
// Xh[bc][r][d] (r<33 real, 33..65 imag) = sum_t D[r][t] * x[bc][t][d].
// Block: one bc x 128 d-cols, 2 waves, 52KB LDS -> 3 blocks/CU. Basis hi+res
// + data hi+res; 3 MFMAs per tile (drop Ar*Br ~2^-18). Also emits bf16 X_low
// pack and chunk-mean.
__global__ __launch_bounds__(128) void dft_mfma(
    const float* __restrict__ X, const bf16_t* __restrict__ dhi,
    const bf16_t* __restrict__ dres, bf16_t* __restrict__ Xh,
    bf16_t* __restrict__ XLr, bf16_t* __restrict__ XLi,
    bf16_t* __restrict__ gmean) {
  const int bc = blockIdx.y;        // 0..255
  const int d0 = blockIdx.x * 128;  // 8 d-tiles
  const int tid = threadIdx.x;      // 0..127
  const int lane = tid & 63, wave = tid >> 6;
  const int mr = lane & 15, q = lane >> 4;
  const int wn = wave * 64;

  __shared__ bf16_t Ahi[80 * 64];
  __shared__ bf16_t Ares[80 * 64];
  __shared__ bf16_t Bh[128 * 64];
  __shared__ bf16_t Br[128 * 64];

  // basis: 5120 elems = 10 chunks of 512; wave-uniform LDS bases
  for (int i = wave; i < 10; i += 2) {
    gld_lds16(dhi + (i * 64 + lane) * 8, Ahi + i * 512);
    gld_lds16(dres + (i * 64 + lane) * 8, Ares + i * 512);
  }

  // B transpose-stage: thread owns d-col (d0+tid); 64 coalesced fp32 loads,
  // split hi/res, ds_write_b128 with XOR slot swizzle (g ^ (tid&7)).
  {
    const float* xc = X + ((long)bc * 64) * 1024 + d0 + tid;
    const int sw = tid & 7;
#pragma unroll
    for (int g = 0; g < 8; g++) {
      bf16x8 vh, vr;
#pragma unroll
      for (int i = 0; i < 8; i++) {
        float v = xc[(long)(g * 8 + i) * 1024];
        bf16_t h = (bf16_t)v;
        vh[i] = h;
        vr[i] = (bf16_t)(v - (float)h);
      }
      *(bf16x8*)&Bh[tid * 64 + ((g ^ sw) << 3)] = vh;
      *(bf16x8*)&Br[tid * 64 + ((g ^ sw) << 3)] = vr;
    }
  }
  __syncthreads();  // drains vmcnt (basis) + lgkm (B writes)

  f32x4 acc[5][4];
#pragma unroll
  for (int i = 0; i < 5; i++)
#pragma unroll
    for (int j = 0; j < 4; j++) acc[i][j] = (f32x4){0.f, 0.f, 0.f, 0.f};

#pragma unroll
  for (int s = 0; s < 2; s++) {
    bf16x8 bh[4], br[4];
#pragma unroll
    for (int ni = 0; ni < 4; ni++) {
      int dcol = wn + ni * 16 + mr;
      int so = (((s * 4 + q) ^ (dcol & 7)) << 3);
      bh[ni] = *(const bf16x8*)&Bh[dcol * 64 + so];
      br[ni] = *(const bf16x8*)&Br[dcol * 64 + so];
    }
#pragma unroll
    for (int mi = 0; mi < 5; mi++) {
      int trow = mi * 16 + mr;
      int so = (((s * 4 + q) ^ (trow & 7)) << 3);
      bf16x8 ah = *(const bf16x8*)&Ahi[trow * 64 + so];
      bf16x8 ar = *(const bf16x8*)&Ares[trow * 64 + so];
#pragma unroll
      for (int ni = 0; ni < 4; ni++) {
        acc[mi][ni] = __builtin_amdgcn_mfma_f32_16x16x32_bf16(
            ah, bh[ni], acc[mi][ni], 0, 0, 0);
        acc[mi][ni] = __builtin_amdgcn_mfma_f32_16x16x32_bf16(
            ah, br[ni], acc[mi][ni], 0, 0, 0);
        acc[mi][ni] = __builtin_amdgcn_mfma_f32_16x16x32_bf16(
            ar, bh[ni], acc[mi][ni], 0, 0, 0);
      }
    }
  }

  const int b = bc >> 6, ch = bc & 63;
  bf16_t* xp = Xh + (long)bc * 66 * 1024 + d0;
#pragma unroll
  for (int mi = 0; mi < 5; mi++) {
#pragma unroll
    for (int r = 0; r < 4; r++) {
      int row = mi * 16 + q * 4 + r;
      if (row >= 66) continue;
#pragma unroll
      for (int ni = 0; ni < 4; ni++) {
        int col = wn + ni * 16 + mr;
        float val = acc[mi][ni][r];
        xp[(long)row * 1024 + col] = (bf16_t)val;
        if (row == 0)
          gmean[(long)bc * 1024 + d0 + col] = (bf16_t)(val * (1.f / 64.f));
        if (row < 4)
          XLr[((long)(b * 256 + ch * 4 + row)) * 1024 + d0 + col] = (bf16_t)val;
        if (row >= 33 && row < 37)
          XLi[((long)(b * 256 + ch * 4 + row - 33)) * 1024 + d0 + col] =
              (bf16_t)val;
      }
    }
  }
}

// ================== 128^2 pipelined GEMM (all epilogues) ===================
// C[M,N] = A[M,K=1024] @ B[N,K]^T. 256 threads = 4 waves (2M x 2N), per-wave
// 64x64 out. 4-slot LDS ring (64KB -> 2 blocks/CU), depth-3 prefetch, counted
// vmcnt (never drains in main loop). Raw s_barrier, one per K-step.
// 1D grid with XCD swizzle: g = (bid%8)*(nwg/8)+bid/8; mt = g/(ntc*zc) so
// each XCD works contiguous m-panels (A stays L2-resident). All grids are
// multiples of 8 -> swizzle bijective.
template <int EMODE>
__global__ __launch_bounds__(256, 2) void gemm128(
    const bf16_t* __restrict__ A0, const bf16_t* __restrict__ A1,
    const bf16_t* __restrict__ B0, const bf16_t* __restrict__ B1,
    int N, int ntc, int zc,
    void* __restrict__ C0v, void* __restrict__ C1v,
    const bf16_t* __restrict__ E0, const bf16_t* __restrict__ E1,
    bf16_t* __restrict__ XhMut,
    const float* __restrict__ gate, const float* __restrict__ alpha_ptr) {
  constexpr int K = 1024;
  constexpr int NT = 32;                  // K/32 K-tiles
  __shared__ bf16_t lds[4][2][128 * 32];  // ring x (A,B) x 8KB = 64KB

  const int nwg = gridDim.x;
  const int g = (blockIdx.x & 7) * (nwg >> 3) + (blockIdx.x >> 3);
  const int per_mt = ntc * zc;
  const int mt = g / per_mt, rem = g - mt * per_mt;
  const int nt = rem % ntc, z = rem / ntc;
  const bf16_t* A = z ? A1 : A0;
  const bf16_t* B = z ? B1 : B0;
  void* Cv = z ? C1v : C0v;
  const bf16_t* E = z ? E1 : E0;
  const int imoff = z ? 33 * 1024 : 0;
  const int m0 = mt * 128, n0 = nt * 128;

  const int tid = threadIdx.x;
  const int lane = tid & 63, wave = tid >> 6;
  const int wm = (wave & 1) * 64, wn = (wave >> 1) * 64;
  const int q = lane >> 4, mr = lane & 15;
  // staging: chunk c = it*256 + tid -> row c>>2, 16B slot c&3 (linear layout)
  const int srow = tid >> 2, sk8 = (tid & 3) * 8;

  f32x4 acc[4][4];
#pragma unroll
  for (int i = 0; i < 4; i++)
#pragma unroll
    for (int j = 0; j < 4; j++) acc[i][j] = (f32x4){0.f, 0.f, 0.f, 0.f};

  // stage K-tile t into ring slot t&3: 4 x gld_lds16 per thread (2 A + 2 B)
  auto stage = [&](int t) {
    const int bi = t & 3;
    const int kb = t * 32;
#pragma unroll
    for (int it = 0; it < 2; it++) {
      gld_lds16(A + (long)(m0 + it * 64 + srow) * K + kb + sk8,
                &lds[bi][0][(it * 256 + wave * 64) * 8]);
      gld_lds16(B + (long)(n0 + it * 64 + srow) * K + kb + sk8,
                &lds[bi][1][(it * 256 + wave * 64) * 8]);
    }
  };

  stage(0);
  stage(1);
  stage(2);

  for (int t = 0; t < NT; t++) {
    // tile t landed; tiles t+1,t+2 (8 loads/thread) remain in flight.
    if (t < NT - 2)
      asm volatile("s_waitcnt vmcnt(8)" ::: "memory");
    else if (t == NT - 2)
      asm volatile("s_waitcnt vmcnt(4)" ::: "memory");
    else
      asm volatile("s_waitcnt vmcnt(0)" ::: "memory");
    __builtin_amdgcn_sched_barrier(0);
    __builtin_amdgcn_s_barrier();  // all waves' tile-t LDS writes now visible
    if (t + 3 < NT) stage(t + 3);  // slot freed before this barrier

    const bf16_t* As_ = &lds[t & 3][0][0];
    const bf16_t* Bs_ = &lds[t & 3][1][0];
    bf16x8 bfr[4];
#pragma unroll
    for (int ni = 0; ni < 4; ni++)
      bfr[ni] = *(const bf16x8*)&Bs_[(wn + ni * 16 + mr) * 32 + q * 8];
    __builtin_amdgcn_s_setprio(1);
#pragma unroll
    for (int mi = 0; mi < 4; mi++) {
      bf16x8 af = *(const bf16x8*)&As_[(wm + mi * 16 + mr) * 32 + q * 8];
#pragma unroll
      for (int ni = 0; ni < 4; ni++)
        acc[mi][ni] = __builtin_amdgcn_mfma_f32_16x16x32_bf16(
            af, bfr[ni], acc[mi][ni], 0, 0, 0);
    }
    __builtin_amdgcn_s_setprio(0);
  }

  float alpha = 0.f;
  if constexpr (EMODE == EP_FUSELOW) alpha = 1.f / (1.f + __expf(-alpha_ptr[0]));
#pragma unroll
  for (int mi = 0; mi < 4; mi++) {
#pragma unroll
    for (int ni = 0; ni < 4; ni++) {
      int col = n0 + wn + ni * 16 + mr;
      int rbase = m0 + wm + mi * 16 + q * 4;
#pragma unroll
      for (int r = 0; r < 4; r++) {
        int row = rbase + r;
        float val = acc[mi][ni][r];
        if constexpr (EMODE == EP_NONE) {
          ((bf16_t*)Cv)[(long)row * N + col] = (bf16_t)val;
        } else if constexpr (EMODE == EP_SIGMOID) {
          ((float*)Cv)[(long)row * N + col] = 1.f / (1.f + __expf(-val));
        } else if constexpr (EMODE == EP_FUSELOW) {
          // E = contiguous bf16 X_low pack, same row/col indexing as C
          float xl = (float)E[(long)row * 1024 + col];
          ((float*)Cv)[(long)row * 1024 + col] = alpha * val + (1.f - alpha) * xl;
        } else {  // EP_HIGH: in-place A_high = val*g + X_high (Xh bf16)
          int bc = row / 29, l = row - bc * 29;
          long x = ((long)bc * 66 + 4 + l) * 1024 + imoff + col;
          XhMut[x] = (bf16_t)fmaf(val, gate[(long)bc * 1024 + col], (float)XhMut[x]);
        }
      }
    }
  }
}

// ====================== MFMA flash attention ===============================
// grid (NH=16, B*4 qtiles=16, 2). block 256 = 4 waves; wave w owns q rows
// [qt*64 + w*16, +16). Block-causal (chunk=4): kt<qt visible, kt==qt masked.
__global__ __launch_bounds__(256) void attn_mfma(const bf16_t* __restrict__ QKVr,
                                                 const bf16_t* __restrict__ QKVi,
                                                 bf16_t* __restrict__ Or_,
                                                 bf16_t* __restrict__ Oi_) {
  const int h = blockIdx.x;
  const int b = blockIdx.y >> 2, qt = blockIdx.y & 3;
  const bf16_t* QKV = blockIdx.z ? QKVi : QKVr;
  bf16_t* O = blockIdx.z ? Oi_ : Or_;
  const int kvh = h >> 2;
  const int tid = threadIdx.x;
  const int lane = tid & 63, wave = tid >> 6;
  const int mr = lane & 15, q4 = lane >> 4;

  __shared__ bf16_t Ks[64 * 72];
  __shared__ bf16_t Vt[64 * 72];
  __shared__ bf16_t Ps[4][16 * 72];

  bf16x8 af[2];
  {
    const bf16_t* qp =
        QKV + (long)(b * 256 + qt * 64 + wave * 16 + mr) * 1536 + h * 64;
    af[0] = *(const bf16x8*)(qp + q4 * 8);
    af[1] = *(const bf16x8*)(qp + 32 + q4 * 8);
  }
  f32x4 Oacc[4];
#pragma unroll
  for (int ni = 0; ni < 4; ni++) Oacc[ni] = (f32x4){0.f, 0.f, 0.f, 0.f};
  float mrow[4], lrow[4];
#pragma unroll
  for (int r = 0; r < 4; r++) { mrow[r] = -1e30f; lrow[r] = 0.f; }

  for (int kt = 0; kt <= qt; kt++) {
#pragma unroll
    for (int it = 0; it < 2; it++) {
      int idx = tid + it * 256;
      int key = idx >> 3, dg = idx & 7;
      const bf16_t* kp = QKV + (long)(b * 256 + kt * 64 + key) * 1536 + 1024 +
                         kvh * 64 + dg * 8;
      *(bf16x8*)&Ks[key * 72 + dg * 8] = *(const bf16x8*)kp;
      bf16x8 vv = *(const bf16x8*)(kp + 256);
#pragma unroll
      for (int j = 0; j < 8; j++) Vt[(dg * 8 + j) * 72 + key] = vv[j];
    }
    __syncthreads();

    f32x4 S[4];
#pragma unroll
    for (int ni = 0; ni < 4; ni++) {
      S[ni] = (f32x4){0.f, 0.f, 0.f, 0.f};
#pragma unroll
      for (int s = 0; s < 2; s++) {
        bf16x8 kb = *(const bf16x8*)&Ks[(ni * 16 + mr) * 72 + s * 32 + q4 * 8];
        S[ni] = __builtin_amdgcn_mfma_f32_16x16x32_bf16(af[s], kb, S[ni], 0, 0, 0);
      }
    }
#pragma unroll
    for (int ni = 0; ni < 4; ni++) {
#pragma unroll
      for (int r = 0; r < 4; r++) {
        float v = S[ni][r] * 0.125f;
        if (kt == qt) {
          int qrow = wave * 16 + q4 * 4 + r;
          int kcol = ni * 16 + mr;
          if ((qrow >> 2) < (kcol >> 2)) v = -1e30f;
        }
        S[ni][r] = v;
      }
    }
#pragma unroll
    for (int r = 0; r < 4; r++) {
      float mx = fmaxf(fmaxf(S[0][r], S[1][r]), fmaxf(S[2][r], S[3][r]));
#pragma unroll
      for (int off = 1; off < 16; off <<= 1) mx = fmaxf(mx, __shfl_xor(mx, off));
      float mn = fmaxf(mrow[r], mx);
      float sc = __expf(mrow[r] - mn);
      mrow[r] = mn;
      float rs = 0.f;
#pragma unroll
      for (int ni = 0; ni < 4; ni++) {
        float p = __expf(S[ni][r] - mn);
        rs += p;
        Ps[wave][(q4 * 4 + r) * 72 + ni * 16 + mr] = (bf16_t)p;
      }
#pragma unroll
      for (int off = 1; off < 16; off <<= 1) rs += __shfl_xor(rs, off);
      lrow[r] = lrow[r] * sc + rs;
#pragma unroll
      for (int ni = 0; ni < 4; ni++) Oacc[ni][r] *= sc;
    }
    bf16x8 pa[2];
    pa[0] = *(const bf16x8*)&Ps[wave][mr * 72 + q4 * 8];
    pa[1] = *(const bf16x8*)&Ps[wave][mr * 72 + 32 + q4 * 8];
#pragma unroll
    for (int ni = 0; ni < 4; ni++) {
#pragma unroll
      for (int s = 0; s < 2; s++) {
        bf16x8 vb = *(const bf16x8*)&Vt[(ni * 16 + mr) * 72 + s * 32 + q4 * 8];
        Oacc[ni] = __builtin_amdgcn_mfma_f32_16x16x32_bf16(pa[s], vb, Oacc[ni], 0, 0, 0);
      }
    }
    __syncthreads();
  }

#pragma unroll
  for (int r = 0; r < 4; r++) {
    float inv = 1.f / lrow[r];
    long row = b * 256 + qt * 64 + wave * 16 + q4 * 4 + r;
#pragma unroll
    for (int ni = 0; ni < 4; ni++)
      O[row * 1024 + h * 64 + ni * 16 + mr] = (bf16_t)(Oacc[ni][r] * inv);
  }
}

// ===================== depthwise causal conv + GELU ========================
__global__ __launch_bounds__(256) void dwconv_kernel(const bf16_t* __restrict__ Xh,
                                                     const float* __restrict__ dwr,
                                                     const float* __restrict__ dwi,
                                                     bf16_t* __restrict__ Gr,
                                                     bf16_t* __restrict__ Gi) {
  const int d = blockIdx.x * 256 + threadIdx.x;
  const int bc = blockIdx.y;
  const float* dw = blockIdx.z ? dwi : dwr;
  bf16_t* G = blockIdx.z ? Gi : Gr;
  const int imoff = blockIdx.z ? 33 * 1024 : 0;
  float w[7];
#pragma unroll
  for (int j = 0; j < 7; j++) w[j] = dw[d * 7 + j];
  float x[29];
#pragma unroll
  for (int l = 0; l < 29; l++)
    x[l] = (float)Xh[((long)bc * 66 + 4 + l) * 1024 + imoff + d];
#pragma unroll
  for (int l = 0; l < 29; l++) {
    float y = 0.f;
#pragma unroll
    for (int j = 0; j < 7; j++) {
      int src = l - 6 + j;
      if (src >= 0) y = fmaf(w[j], x[src], y);
    }
    float ge = 0.5f * y * (1.f + erff(y * 0.7071067811865475f));
    G[((long)bc * 29 + l) * 1024 + d] = (bf16_t)ge;
  }
}

// ======================= irfft via MFMA + fp32 low =========================
// out[bc*64+t][d] = sum_k T[t][k]*XhHigh[bc][k][d] (MFMA, basis hi+res bf16)
//                 + fp32 low-bin part from Af (f=0..3) via Tlow.
// Block: one bc x 128 d-cols, 2 waves, 34KB LDS -> 4 blocks/CU.
__global__ __launch_bounds__(128) void irfft_mfma(
    const bf16_t* __restrict__ Xh, const float* __restrict__ Afr,
    const float* __restrict__ Afi, const bf16_t* __restrict__ bhi,
    const bf16_t* __restrict__ bres, const float* __restrict__ tlow,
    float* __restrict__ out) {
  const int bc = blockIdx.y;        // 0..255
  const int d0 = blockIdx.x * 128;  // 8 d-tiles
  const int tid = threadIdx.x;      // 0..127
  const int lane = tid & 63, wave = tid >> 6;
  const int mr = lane & 15, q = lane >> 4;
  const int wn = wave * 64;

  __shared__ bf16_t Ahi[64 * 64];
  __shared__ bf16_t Ares[64 * 64];
  __shared__ bf16_t Bs[128 * 64];
  __shared__ float Tl[64 * 8];

  // basis tables: linear gld_lds (already pre-swizzled in global)
  for (int i = wave; i < 8; i += 2) {
    gld_lds16(bhi + (i * 64 + lane) * 8, Ahi + i * 512);
    gld_lds16(bres + (i * 64 + lane) * 8, Ares + i * 512);
  }
  ((float4*)Tl)[tid] = ((const float4*)tlow)[tid];  // 128 x 16B = 2KB

  // B transpose-stage: thread owns d-column (d0+tid); rows k=0..56 map to
  // Xh rows 4..32 (real f=4..32) and 37..64 (imag f=4..31); 57..63 zero.
  {
    const bf16_t* xc = Xh + (long)bc * 66 * 1024 + d0 + tid;
    const int sw = tid & 7;
#pragma unroll
    for (int g = 0; g < 8; g++) {
      bf16x8 v;
#pragma unroll
      for (int i = 0; i < 8; i++) {
        int j = g * 8 + i;
        int row = (j < 29) ? (4 + j) : (8 + j);
        v[i] = (j < 57) ? xc[(long)row * 1024] : (bf16_t)0.f;
      }
      *(bf16x8*)&Bs[tid * 64 + ((g ^ sw) << 3)] = v;
    }
  }
  __syncthreads();  // drains vmcnt -> basis complete; ds_writes complete

  f32x4 acc[4][4];
#pragma unroll
  for (int i = 0; i < 4; i++)
#pragma unroll
    for (int j = 0; j < 4; j++) acc[i][j] = (f32x4){0.f, 0.f, 0.f, 0.f};

#pragma unroll
  for (int s = 0; s < 2; s++) {
    bf16x8 bfv[4];
#pragma unroll
    for (int ni = 0; ni < 4; ni++) {
      int dcol = wn + ni * 16 + mr;
      bfv[ni] = *(const bf16x8*)&Bs[dcol * 64 + (((s * 4 + q) ^ (dcol & 7)) << 3)];
    }
#pragma unroll
    for (int mi = 0; mi < 4; mi++) {
      int trow = mi * 16 + mr;
      int so = (((s * 4 + q) ^ (trow & 7)) << 3);
      bf16x8 ah = *(const bf16x8*)&Ahi[trow * 64 + so];
      bf16x8 ar = *(const bf16x8*)&Ares[trow * 64 + so];
#pragma unroll
      for (int ni = 0; ni < 4; ni++) {
        acc[mi][ni] = __builtin_amdgcn_mfma_f32_16x16x32_bf16(
            ah, bfv[ni], acc[mi][ni], 0, 0, 0);
        acc[mi][ni] = __builtin_amdgcn_mfma_f32_16x16x32_bf16(
            ar, bfv[ni], acc[mi][ni], 0, 0, 0);
      }
    }
  }

  // fp32 low-bin epilogue: rows f=0..3 of Af (alpha-fused), Tlow basis
  const int arow = (bc >> 6) * 256 + (bc & 63) * 4;
  float R[4][7];
#pragma unroll
  for (int ni = 0; ni < 4; ni++) {
    long ab = (long)arow * 1024 + d0 + wn + ni * 16 + mr;
    R[ni][0] = Afr[ab];
    R[ni][1] = Afr[ab + 1024];
    R[ni][2] = Afi[ab + 1024];
    R[ni][3] = Afr[ab + 2048];
    R[ni][4] = Afi[ab + 2048];
    R[ni][5] = Afr[ab + 3072];
    R[ni][6] = Afi[ab + 3072];
  }
  const long obase = ((long)bc * 64) * 1024 + d0;
#pragma unroll
  for (int mi = 0; mi < 4; mi++) {
#pragma unroll
    for (int r = 0; r < 4; r++) {
      int t = mi * 16 + q * 4 + r;
      const float* tl = &Tl[t * 8];
#pragma unroll
      for (int ni = 0; ni < 4; ni++) {
        float low = tl[0] * R[ni][0];
        low = fmaf(tl[1], R[ni][1], low);
        low = fmaf(tl[2], R[ni][2], low);
        low = fmaf(tl[3], R[ni][3], low);
        low = fmaf(tl[4], R[ni][4], low);
        low = fmaf(tl[5], R[ni][5], low);
        low = fmaf(tl[6], R[ni][6], low);
        out[obase + (long)t * 1024 + wn + ni * 16 + mr] = acc[mi][ni][r] + low;
      }
    }
  }
}

// ============================ launcher =====================================
extern "C" void kernel_launch(void* const* d_in, const int* in_sizes, int n_in,
                              void* d_out, int out_size, void* d_ws, size_t ws_size,
                              hipStream_t stream) {
  const float* hidden = (const float*)d_in[0];
  const float* q_w = (const float*)d_in[1];
  const float* k_w = (const float*)d_in[2];
  const float* v_w = (const float*)d_in[3];
  const float* o_w = (const float*)d_in[4];
  const float* dw_r = (const float*)d_in[5];
  const float* pw_r = (const float*)d_in[6];
  const float* dw_i = (const float*)d_in[7];
  const float* pw_i = (const float*)d_in[8];
  const float* gate_w = (const float*)d_in[9];
  const float* alpha_raw = (const float*)d_in[10];
  float* out = (float*)d_out;

  float* ws = (float*)d_ws;
  // fp32 region
  float* Afr = ws;                       // 1024*1024
  float* Afi = Afr + 1048576;
  float* gg = Afi + 1048576;             // 256*1024
  // bf16 region
  bf16_t* bws = (bf16_t*)(gg + 262144);
  bf16_t* Xh = bws;                      // 256*66*1024 = 17,301,504 bf16
  bf16_t* Wqkv_b = Xh + 17301504;        // 1536*1024
  bf16_t* ow_b = Wqkv_b + 1572864;       // 1024*1024
  bf16_t* gw_b = ow_b + 1048576;
  bf16_t* pwr_b = gw_b + 1048576;
  bf16_t* pwi_b = pwr_b + 1048576;
  bf16_t* XLr = pwi_b + 1048576;         // 1024*1024
  bf16_t* XLi = XLr + 1048576;
  bf16_t* gmean = XLi + 1048576;         // 256*1024
  bf16_t* QKVbr = gmean + 262144;        // 1024*1536
  bf16_t* QKVbi = QKVbr + 1572864;
  bf16_t* Obr = QKVbi + 1572864;         // 1024*1024
  bf16_t* Obi = Obr + 1048576;
  bf16_t* Gr = Obi + 1048576;            // 7424*1024
  bf16_t* Gi = Gr + 7602176;
  bf16_t* bhi = Gi + 7602176;            // 64*64 irfft basis hi
  bf16_t* bres = bhi + 4096;             // 64*64 irfft basis residual
  bf16_t* dbhi = bres + 4096;            // 80*64 dft basis hi
  bf16_t* dbres = dbhi + 5120;           // 80*64 dft basis residual
  float* tlowp = (float*)(dbres + 5120); // 64*8 fp32

  // 0) basis tables (pre-swizzled)
  mk_basis<<<38, 256, 0, stream>>>(dbhi, dbres, bhi, bres, tlowp);
  // 1) rfft via MFMA -> bf16 Xh + bf16 X_low pack + bf16 chunk-mean
  dft_mfma<<<dim3(8, 256), 128, 0, stream>>>(hidden, dbhi, dbres, Xh, XLr,
                                             XLi, gmean);
  // 2) weights -> bf16 (single launch)
  prep_w<<<5632, 256, 0, stream>>>(q_w, k_w, v_w, o_w, gate_w, pw_r, pw_i,
                                   Wqkv_b, ow_b, gw_b, pwr_b, pwi_b);
  // 3) QKV projections (real & imag), bf16 out: M=1024, N=1536, 192 blocks
  gemm128<EP_NONE><<<192, 256, 0, stream>>>(
      XLr, XLi, Wqkv_b, Wqkv_b, 1536, 12, 2, QKVbr, QKVbi, nullptr, nullptr,
      nullptr, nullptr, nullptr);
  // 4) gate = sigmoid(mean @ gate_w^T): M=256, N=1024, 16 blocks
  gemm128<EP_SIGMOID><<<16, 256, 0, stream>>>(
      gmean, gmean, gw_b, gw_b, 1024, 8, 1, gg, gg, nullptr, nullptr,
      nullptr, nullptr, nullptr);
  // 5) MFMA flash attention (real & imag), bf16 O out
  attn_mfma<<<dim3(16, 16, 2), 256, 0, stream>>>(QKVbr, QKVbi, Obr, Obi);
  // 6) O projection + alpha*A_low + (1-alpha)*X_low -> fp32 Af: 128 blocks
  gemm128<EP_FUSELOW><<<128, 256, 0, stream>>>(
      Obr, Obi, ow_b, ow_b, 1024, 8, 2, Afr, Afi, XLr, XLi,
      nullptr, nullptr, alpha_raw);
  // 7) depthwise causal conv + exact GELU on high bins, bf16 out
  dwconv_kernel<<<dim3(4, 256, 2), 256, 0, stream>>>(Xh, dw_r, dw_i, Gr, Gi);
  // 8) pointwise conv + gate + residual, in-place into Xh high rows:
  //    M=7424, 928 blocks
  gemm128<EP_HIGH><<<928, 256, 0, stream>>>(
      Gr, Gi, pwr_b, pwi_b, 1024, 8, 2, nullptr, nullptr, nullptr, nullptr,
      Xh, gg, nullptr);
  // 9) irfft via MFMA + fp32 low-bin epilogue
  irfft_mfma<<<dim3(8, 256), 128, 0, stream>>>(Xh, Afr, Afi, bhi, bres,
                                               tlowp, out);
}